// Round 13
// baseline (349.629 us; speedup 1.0000x reference)
//
#include <hip/hip_runtime.h>
#include <math.h>

#define B_   8
#define C_   768
#define T_   1024
#define BT_  (B_*T_)       // 8192
#define WSZ  (C_*C_)       // 589824 per weight matrix

using f16x8 = __attribute__((ext_vector_type(8))) _Float16;
using f32x4 = __attribute__((ext_vector_type(4))) float;
typedef unsigned short u16;

// ---- fp16 helpers ----
__device__ inline u16 f16b(float x) {
    _Float16 h = (_Float16)x;
    return __builtin_bit_cast(u16, h);
}
__device__ inline float f16f(u16 b) {
    return (float)__builtin_bit_cast(_Float16, b);
}

// Direct global->LDS DMA, 16B/lane (used by attn only now).
typedef const __attribute__((address_space(1))) unsigned int gas_uint;
typedef __attribute__((address_space(3))) unsigned int las_uint;
__device__ inline void gld16(const u16* __restrict__ g, u16* l) {
    __builtin_amdgcn_global_load_lds((gas_uint*)g, (las_uint*)l, 16, 0, 0);
}

// ---------------------------------------------------------------------------
// Kernel 0: all 5 weight mats fp32 -> fp16 in one launch.
// ---------------------------------------------------------------------------
__global__ __launch_bounds__(256) void wconv_all(
    const float* __restrict__ W0, const float* __restrict__ W1,
    const float* __restrict__ W2, const float* __restrict__ W3,
    const float* __restrict__ W4, u16* __restrict__ wbuf) {
    int mat = blockIdx.y;
    const float* W = (mat == 0) ? W0 : (mat == 1) ? W1 : (mat == 2) ? W2
                   : (mat == 3) ? W3 : W4;
    u16* o = wbuf + (size_t)mat * WSZ;
    int i = (blockIdx.x * 256 + threadIdx.x) * 4;
    float4 w = *(const float4*)(W + i);
    ushort4 h;
    h.x = f16b(w.x);
    h.y = f16b(w.y);
    h.z = f16b(w.z);
    h.w = f16b(w.w);
    *(ushort4*)(o + i) = h;
}

// ---------------------------------------------------------------------------
// Kernel 1: LayerNorm, coalesced 16-token tile (R9, kept).
// ---------------------------------------------------------------------------
__global__ __launch_bounds__(256) void ln_kernel(const float* __restrict__ x,
                                                 const float* __restrict__ gamma,
                                                 const float* __restrict__ beta,
                                                 u16* __restrict__ xh) {
    int b = blockIdx.y;
    int t0 = blockIdx.x * 16;
    int tid = threadIdx.x;
    int tx = tid & 15;          // t offset
    int cg = tid >> 4;          // c group 0..15
    const float* xb = x + (size_t)b * C_ * T_ + t0 + tx;

    float v[48];
    float s = 0.f, sq = 0.f;
    #pragma unroll
    for (int i = 0; i < 48; ++i) {
        float val = xb[(size_t)(i * 16 + cg) * T_];
        v[i] = val; s += val; sq += val * val;
    }
    __shared__ float rs_[16][16], rq_[16][16];   // [cg][tx]
    rs_[cg][tx] = s;
    rq_[cg][tx] = sq;
    __syncthreads();
    __shared__ float mu_[16], rstd_[16];
    if (tid < 16) {
        float S = 0.f, Q = 0.f;
        #pragma unroll
        for (int k = 0; k < 16; ++k) { S += rs_[k][tid]; Q += rq_[k][tid]; }
        float mu = S * (1.0f / 768.0f);
        float var = Q * (1.0f / 768.0f) - mu * mu;
        mu_[tid] = mu;
        rstd_[tid] = 1.0f / sqrtf(var + 1e-5f);
    }
    __syncthreads();
    float mu = mu_[tx], rstd = rstd_[tx];
    __shared__ u16 Lt[16][776];                  // +8 u16 pad
    #pragma unroll
    for (int i = 0; i < 48; ++i) {
        int c = i * 16 + cg;
        Lt[tx][c] = f16b((v[i] - mu) * rstd * gamma[c] + beta[c]);
    }
    __syncthreads();
    size_t obase = ((size_t)b * 1024 + t0) * C_;
    #pragma unroll
    for (int st = 0; st < 12; ++st) {
        int idx = st * 256 + tid;
        int t = idx / 192, c4 = idx % 192;
        *(ushort4*)(xh + obase + (size_t)t * C_ + c4 * 4) = *(ushort4*)&Lt[t][c4 * 4];
    }
}

// ---------------------------------------------------------------------------
// Kernel 2: fused QKVG GEMM, fp16 MFMA. R13: BARRIER-FREE wave-private
// register double-buffer -- the last untested schedule cell.
// Evidence: R7 (no barrier, no prefetch) = 146us latency-exposed;
// R12 (prefetch, barriers) = 90.4us convoy-bound (one HBM-miss stalls all
// 12 waves at the vmcnt(0)+s_barrier). Combine: direct-global fragments
// (R7-verified mapping), B held 1 K-step ahead in registers, A JIT-loaded
// inside the step. No LDS, no __syncthreads -- compiler emits COUNTED
// vmcnt for register loads (G7), so B(t+1) latency hides under STEP(t)'s
// 16 MFMA, and waves never wait on each other.
// Regs: acc 64 + 2xBbuf 32 + A 16 + addr ~ 125 -> (256,2) cap 128
// (empirical cap = 256/arg: R5 (256,4)->64 spill cliff; R6 (256,3)->84).
// ---------------------------------------------------------------------------
__global__ __launch_bounds__(256, 2) void qkvg_mfma(
    const u16* __restrict__ xh, const u16* __restrict__ wmats,
    const float* __restrict__ bq, const float* __restrict__ bk,
    const float* __restrict__ bv, const float* __restrict__ bg,
    u16* __restrict__ qh, u16* __restrict__ kh,
    u16* __restrict__ vth, u16* __restrict__ g) {
    int bx = blockIdx.x;            // m tile 0..63
    int by = blockIdx.y;            // 0..23
    int mat = by / 6;
    int n0  = (by % 6) * 128;
    int m0  = bx * 128;
    const u16* Wh = wmats + (size_t)mat * WSZ;
    const float* bias = (mat == 0) ? bq : (mat == 1) ? bk : (mat == 2) ? bv : bg;

    int tid  = threadIdx.x;
    int lane = tid & 63, wid = tid >> 6;
    int wm = (wid & 1) * 64, wn = (wid >> 1) * 64;
    int fr = lane & 15, rq = (lane >> 4) * 4;

    f32x4 acc[4][4];
    #pragma unroll
    for (int i = 0; i < 4; ++i)
        #pragma unroll
        for (int j = 0; j < 4; ++j)
            acc[i][j] = (f32x4){0.f, 0.f, 0.f, 0.f};

    // direct-global fragment rows (R7-verified): lane l = row (l&15),
    // k-chunk (l>>4)*8 of each 16x32 fragment
    const u16* Ar = xh + (size_t)(m0 + wm + fr) * 768 + (lane >> 4) * 8;
    const u16* Br = Wh + (size_t)(n0 + wn + fr) * 768 + (lane >> 4) * 8;

    f16x8 pB0[4], pB1[4];
    #define LOADB(dst, T) do { int kk0 = (T) * 32; \
        dst[0] = *(const f16x8*)(Br + kk0); \
        dst[1] = *(const f16x8*)(Br + 12288 + kk0); \
        dst[2] = *(const f16x8*)(Br + 24576 + kk0); \
        dst[3] = *(const f16x8*)(Br + 36864 + kk0); \
    } while (0)
    #define STEP(BREG, T) do { int kk0 = (T) * 32; \
        f16x8 fa[4]; \
        fa[0] = *(const f16x8*)(Ar + kk0); \
        fa[1] = *(const f16x8*)(Ar + 12288 + kk0); \
        fa[2] = *(const f16x8*)(Ar + 24576 + kk0); \
        fa[3] = *(const f16x8*)(Ar + 36864 + kk0); \
        if (mat == 2) { \
            _Pragma("unroll") \
            for (int mi = 0; mi < 4; ++mi) \
                _Pragma("unroll") \
                for (int ni = 0; ni < 4; ++ni) \
                    acc[mi][ni] = __builtin_amdgcn_mfma_f32_16x16x32_f16(BREG[ni], fa[mi], acc[mi][ni], 0, 0, 0); \
        } else { \
            _Pragma("unroll") \
            for (int mi = 0; mi < 4; ++mi) \
                _Pragma("unroll") \
                for (int ni = 0; ni < 4; ++ni) \
                    acc[mi][ni] = __builtin_amdgcn_mfma_f32_16x16x32_f16(fa[mi], BREG[ni], acc[mi][ni], 0, 0, 0); \
        } \
    } while (0)

    LOADB(pB0, 0);
    for (int t = 0; t < 24; t += 2) {
        LOADB(pB1, t + 1);          // issue t+1's B; latency hides under STEP(t)
        STEP(pB0, t);
        if (t + 2 < 24) LOADB(pB0, t + 2);
        STEP(pB1, t + 1);
    }
    #undef LOADB
    #undef STEP
    // epilogue: C/D layout col=lane&15, row=(lane>>4)*4+reg
    if (mat == 2) {
        int bb = m0 >> 10;
        #pragma unroll
        for (int mi = 0; mi < 4; ++mi) {
            int tok = m0 + wm + mi * 16 + fr;
            int tl  = tok & 1023;
            #pragma unroll
            for (int ni = 0; ni < 4; ++ni) {
                #pragma unroll
                for (int rg = 0; rg < 4; ++rg) {
                    int ch = n0 + wn + ni * 16 + rq + rg;
                    float val = acc[mi][ni][rg] + bias[ch];
                    size_t addr = ((size_t)((bb * 12 + (ch >> 6)) * 64 + (ch & 63))) * 1024 + tl;
                    vth[addr] = f16b(val);
                }
            }
        }
    } else {
        u16* oh = (mat == 0) ? qh : (mat == 1) ? kh : g;
        float scale = (mat == 0) ? 0.125f : 1.0f;
        #pragma unroll
        for (int ni = 0; ni < 4; ++ni) {
            int col = n0 + wn + ni * 16 + fr;
            float bb = bias[col];
            #pragma unroll
            for (int mi = 0; mi < 4; ++mi) {
                int row = m0 + wm + mi * 16 + rq;
                #pragma unroll
                for (int rg = 0; rg < 4; ++rg) {
                    float val = (acc[mi][ni][rg] + bb) * scale;
                    oh[(size_t)(row + rg) * 768 + col] = f16b(val);
                }
            }
        }
    }
}

// ---------------------------------------------------------------------------
// Kernel 3: MFMA flash attention, fp16, swapped QK^T, QBLK=128,
// gld_lds K/V staging (R11/R12, unchanged).
// ---------------------------------------------------------------------------
__global__ __launch_bounds__(256, 3) void attn_mfma(
    const u16* __restrict__ qhg, const u16* __restrict__ khg,
    const u16* __restrict__ vthg, const u16* __restrict__ gbf,
    u16* __restrict__ yh) {
    int qt = blockIdx.x;   // 0..7 (128 q-rows)
    int h  = blockIdx.y;   // 0..11
    int b  = blockIdx.z;   // 0..7
    __shared__ __attribute__((aligned(16))) u16 Kh[2 * 4096], Vh[2 * 4096];
    __shared__ u16 Ps[64 * 72];
    int tid = threadIdx.x;
    int lane = tid & 63, w = tid >> 6;
    int fr = lane & 15, quad = lane >> 4, fq = quad * 8;

    size_t qbaseA = ((size_t)(b * 1024 + qt * 128)) * 768 + h * 64;
    size_t qbaseB = qbaseA + (size_t)64 * 768;
    size_t kbase = ((size_t)(b * 1024)) * 768 + h * 64;
    size_t vbase = ((size_t)((b * 12 + h) * 64)) * 1024;

    f16x8 aqA[2], aqB[2];
    #pragma unroll
    for (int kk = 0; kk < 2; ++kk) {
        size_t ro = (size_t)(w * 16 + fr) * 768 + kk * 32 + fq;
        aqA[kk] = *(const f16x8*)(qhg + qbaseA + ro);
        aqB[kk] = *(const f16x8*)(qhg + qbaseB + ro);
    }

    float m_A = -1e30f, l_A = 0.0f, m_B = -1e30f, l_B = 0.0f;
    f32x4 OA[4], OB[4];
    #pragma unroll
    for (int i = 0; i < 4; ++i) {
        OA[i] = (f32x4){0.f, 0.f, 0.f, 0.f};
        OB[i] = (f32x4){0.f, 0.f, 0.f, 0.f};
    }

    // gld_lds staging: wave w owns fragment blocks f0 = 2w, f0+1
    int f0 = 2 * w;
    int f1 = f0 + 1;
    const u16* kgA = khg + kbase + (size_t)((f0 & 3) * 16 + fr) * 768 + (f0 >> 2) * 32 + (lane >> 4) * 8;
    const u16* kgB = khg + kbase + (size_t)((f1 & 3) * 16 + fr) * 768 + (f1 >> 2) * 32 + (lane >> 4) * 8;
    const u16* vgA = vthg + vbase + (size_t)((f0 & 3) * 16 + fr) * 1024 + (f0 >> 2) * 32 + (lane >> 4) * 8;
    const u16* vgB = vthg + vbase + (size_t)((f1 & 3) * 16 + fr) * 1024 + (f1 >> 2) * 32 + (lane >> 4) * 8;
    int ldA = f0 * 512 + lane * 8;
    int ldB = ldA + 512;

    #define STAGE(ST, BUF) do { \
        size_t ko = (size_t)(ST) * 49152; \
        size_t vo = (size_t)(ST) * 64; \
        int bo_ = (BUF) * 4096; \
        gld16(kgA + ko, Kh + bo_ + ldA); \
        gld16(kgB + ko, Kh + bo_ + ldB); \
        gld16(vgA + vo, Vh + bo_ + ldA); \
        gld16(vgB + vo, Vh + bo_ + ldB); \
    } while (0)

    // one Q-strip against the staged K/V tile in buf[cur]
    #define STRIP(AQ, MS, LS, OACC) do { \
        f32x4 sacc[4]; \
        _Pragma("unroll") \
        for (int nt = 0; nt < 4; ++nt) sacc[nt] = (f32x4){0.f, 0.f, 0.f, 0.f}; \
        _Pragma("unroll") \
        for (int nt = 0; nt < 4; ++nt) \
            _Pragma("unroll") \
            for (int kk = 0; kk < 2; ++kk) { \
                f16x8 kb = *(const f16x8*)(Kh + cur * 4096 + (kk * 4 + nt) * 512 + lane * 8); \
                sacc[nt] = __builtin_amdgcn_mfma_f32_16x16x32_f16(kb, AQ[kk], sacc[nt], 0, 0, 0); \
            } \
        float mx = -1e30f; \
        _Pragma("unroll") \
        for (int nt = 0; nt < 4; ++nt) \
            _Pragma("unroll") \
            for (int rg = 0; rg < 4; ++rg) mx = fmaxf(mx, sacc[nt][rg]); \
        mx = fmaxf(mx, __shfl_xor(mx, 16)); \
        mx = fmaxf(mx, __shfl_xor(mx, 32)); \
        float mn = fmaxf(MS, mx); \
        float al = __expf(MS - mn); \
        MS = mn; \
        float rs = 0.0f; \
        _Pragma("unroll") \
        for (int nt = 0; nt < 4; ++nt) \
            _Pragma("unroll") \
            for (int rg = 0; rg < 4; ++rg) { \
                float p = __expf(sacc[nt][rg] - mn); \
                sacc[nt][rg] = p; \
                rs += p; \
            } \
        rs += __shfl_xor(rs, 16); \
        rs += __shfl_xor(rs, 32); \
        LS = LS * al + rs; \
        int prow = (w * 16 + fr) * 72; \
        _Pragma("unroll") \
        for (int nt = 0; nt < 4; ++nt) { \
            ushort4 hp; \
            hp.x = f16b(sacc[nt][0]); \
            hp.y = f16b(sacc[nt][1]); \
            hp.z = f16b(sacc[nt][2]); \
            hp.w = f16b(sacc[nt][3]); \
            *(ushort4*)&Ps[prow + nt * 16 + quad * 4] = hp; \
        } \
        float alr[4]; \
        _Pragma("unroll") \
        for (int rg = 0; rg < 4; ++rg) alr[rg] = __shfl(al, quad * 4 + rg, 16); \
        _Pragma("unroll") \
        for (int dn = 0; dn < 4; ++dn) \
            _Pragma("unroll") \
            for (int rg = 0; rg < 4; ++rg) OACC[dn][rg] *= alr[rg]; \
        _Pragma("unroll") \
        for (int kk = 0; kk < 2; ++kk) { \
            f16x8 pa = *(const f16x8*)&Ps[(w * 16 + fr) * 72 + fq + kk * 32]; \
            _Pragma("unroll") \
            for (int dn = 0; dn < 4; ++dn) { \
                f16x8 vb = *(const f16x8*)(Vh + cur * 4096 + (kk * 4 + dn) * 512 + lane * 8); \
                OACC[dn] = __builtin_amdgcn_mfma_f32_16x16x32_f16(pa, vb, OACC[dn], 0, 0, 0); \
            } \
        } \
    } while (0)

    STAGE(0, 0);
    __syncthreads();               // st0 staged (vmcnt drained by barrier)
    int cur = 0;
    for (int st = 0; st < 16; ++st) {
        int nxt = cur ^ 1;
        if (st + 1 < 16) STAGE(st + 1, nxt);   // issue; drains at bottom barrier
        STRIP(aqA, m_A, l_A, OA);
        STRIP(aqB, m_B, l_B, OB);
        __syncthreads();
        cur = nxt;
    }
    #undef STAGE
    #undef STRIP
    // epilogue: normalize, sigmoid gate, fp16 y store (both strips)
    float invA[4], invB[4];
    #pragma unroll
    for (int rg = 0; rg < 4; ++rg) {
        invA[rg] = 1.0f / __shfl(l_A, quad * 4 + rg, 16);
        invB[rg] = 1.0f / __shfl(l_B, quad * 4 + rg, 16);
    }
    int tokA0 = b * 1024 + qt * 128 + w * 16;
    #pragma unroll
    for (int dn = 0; dn < 4; ++dn) {
        int ch = h * 64 + dn * 16 + fr;
        #pragma unroll
        for (int rg = 0; rg < 4; ++rg) {
            int tok = tokA0 + quad * 4 + rg;
            float gv = f16f(gbf[(size_t)tok * 768 + ch]);
            float sg = 1.0f / (1.0f + __expf(-gv));
            yh[(size_t)tok * 768 + ch] = f16b(OA[dn][rg] * invA[rg] * sg);
            int tok2 = tok + 64;
            float gv2 = f16f(gbf[(size_t)tok2 * 768 + ch]);
            float sg2 = 1.0f / (1.0f + __expf(-gv2));
            yh[(size_t)tok2 * 768 + ch] = f16b(OB[dn][rg] * invB[rg] * sg2);
        }
    }
}

// ---------------------------------------------------------------------------
// Kernel 4: out = y @ Wo^T + bo -> (B, C, T). R13: same barrier-free
// register-DB transform (A=Wo JIT, B=yh prefetched 1 step ahead).
// ---------------------------------------------------------------------------
__global__ __launch_bounds__(256, 2) void out_mfma(
    const u16* __restrict__ yh, const u16* __restrict__ woh,
    const float* __restrict__ bo, float* __restrict__ out) {
    int bx = blockIdx.x;   // c tile 0..5
    int by = blockIdx.y;   // t tile 0..63
    int m0 = bx * 128;     // c
    int n0 = by * 128;     // t

    int tid  = threadIdx.x;
    int lane = tid & 63, wid = tid >> 6;
    int wm = (wid & 1) * 64, wn = (wid >> 1) * 64;
    int fr = lane & 15, rq = (lane >> 4) * 4;

    f32x4 acc[4][4];
    #pragma unroll
    for (int i = 0; i < 4; ++i)
        #pragma unroll
        for (int j = 0; j < 4; ++j)
            acc[i][j] = (f32x4){0.f, 0.f, 0.f, 0.f};

    const u16* Ar = woh + (size_t)(m0 + wm + fr) * 768 + (lane >> 4) * 8;
    const u16* Br = yh + (size_t)(n0 + wn + fr) * 768 + (lane >> 4) * 8;

    f16x8 pB0[4], pB1[4];
    #define LOADB(dst, T) do { int kk0 = (T) * 32; \
        dst[0] = *(const f16x8*)(Br + kk0); \
        dst[1] = *(const f16x8*)(Br + 12288 + kk0); \
        dst[2] = *(const f16x8*)(Br + 24576 + kk0); \
        dst[3] = *(const f16x8*)(Br + 36864 + kk0); \
    } while (0)
    #define STEP(BREG, T) do { int kk0 = (T) * 32; \
        f16x8 fa[4]; \
        fa[0] = *(const f16x8*)(Ar + kk0); \
        fa[1] = *(const f16x8*)(Ar + 12288 + kk0); \
        fa[2] = *(const f16x8*)(Ar + 24576 + kk0); \
        fa[3] = *(const f16x8*)(Ar + 36864 + kk0); \
        _Pragma("unroll") \
        for (int mi = 0; mi < 4; ++mi) \
            _Pragma("unroll") \
            for (int ni = 0; ni < 4; ++ni) \
                acc[mi][ni] = __builtin_amdgcn_mfma_f32_16x16x32_f16(fa[mi], BREG[ni], acc[mi][ni], 0, 0, 0); \
    } while (0)

    LOADB(pB0, 0);
    for (int t = 0; t < 24; t += 2) {
        LOADB(pB1, t + 1);
        STEP(pB0, t);
        if (t + 2 < 24) LOADB(pB0, t + 2);
        STEP(pB1, t + 1);
    }
    #undef LOADB
    #undef STEP
    int bb = n0 >> 10;
    #pragma unroll
    for (int ni = 0; ni < 4; ++ni) {
        int colg = n0 + wn + ni * 16 + fr;
        int tl = colg & 1023;
        #pragma unroll
        for (int mi = 0; mi < 4; ++mi) {
            int row = m0 + wm + mi * 16 + rq;
            #pragma unroll
            for (int rg = 0; rg < 4; ++rg) {
                float val = acc[mi][ni][rg] + bo[row + rg];
                out[((size_t)bb * 768 + row + rg) * 1024 + tl] = val;
            }
        }
    }
}

extern "C" void kernel_launch(void* const* d_in, const int* in_sizes, int n_in,
                              void* d_out, int out_size, void* d_ws, size_t ws_size,
                              hipStream_t stream) {
    const float* x     = (const float*)d_in[0];
    const float* Wq    = (const float*)d_in[1];
    const float* bq    = (const float*)d_in[2];
    const float* Wk    = (const float*)d_in[3];
    const float* bk    = (const float*)d_in[4];
    const float* Wv    = (const float*)d_in[5];
    const float* bv    = (const float*)d_in[6];
    const float* Wo    = (const float*)d_in[7];
    const float* bo    = (const float*)d_in[8];
    const float* Wg    = (const float*)d_in[9];
    const float* bg    = (const float*)d_in[10];
    const float* gamma = (const float*)d_in[11];
    const float* beta  = (const float*)d_in[12];
    float* out = (float*)d_out;

    // workspace (ushort, all fp16): xn|q|k|vt|g | wbuf[Wq,Wk,Wv,Wg,Wo]
    const size_t S = (size_t)BT_ * C_;
    u16* xn   = (u16*)d_ws;
    u16* qh   = xn + S;
    u16* kh   = qh + S;
    u16* vth  = kh + S;
    u16* g_bf = vth + S;
    u16* wbuf = g_bf + S;
    u16* y_h  = xn;          // alias: xn dead after qkvg

    wconv_all<<<dim3(WSZ / 1024, 5), 256, 0, stream>>>(Wq, Wk, Wv, Wg, Wo, wbuf);
    ln_kernel<<<dim3(64, 8), 256, 0, stream>>>(x, gamma, beta, xn);
    qkvg_mfma<<<dim3(64, 24), 256, 0, stream>>>(xn, wbuf, bq, bk, bv, bg,
                                                qh, kh, vth, g_bf);
    attn_mfma<<<dim3(8, 12, 8), 256, 0, stream>>>(qh, kh, vth, g_bf, y_h);
    out_mfma<<<dim3(6, 64), 256, 0, stream>>>(y_h, wbuf + (size_t)4 * WSZ, bo, out);
}

// Round 14
// 280.179 us; speedup vs baseline: 1.2479x; 1.2479x over previous
//
#include <hip/hip_runtime.h>
#include <math.h>

#define B_   8
#define C_   768
#define T_   1024
#define BT_  (B_*T_)       // 8192
#define WSZ  (C_*C_)       // 589824 per weight matrix

using f16x8 = __attribute__((ext_vector_type(8))) _Float16;
using f32x4 = __attribute__((ext_vector_type(4))) float;
typedef unsigned short u16;

// ---- fp16 helpers ----
__device__ inline u16 f16b(float x) {
    _Float16 h = (_Float16)x;
    return __builtin_bit_cast(u16, h);
}
__device__ inline float f16f(u16 b) {
    return (float)__builtin_bit_cast(_Float16, b);
}

// Direct global->LDS DMA, 16B/lane. HW: dest = readfirstlane(ptr) + lane*16.
// Callers pass lds = base + lane*8 (u16), base wave-uniform. (R3/R11/R12-verified.)
typedef const __attribute__((address_space(1))) unsigned int gas_uint;
typedef __attribute__((address_space(3))) unsigned int las_uint;
__device__ inline void gld16(const u16* __restrict__ g, u16* l) {
    __builtin_amdgcn_global_load_lds((gas_uint*)g, (las_uint*)l, 16, 0, 0);
}

// ---------------------------------------------------------------------------
// Kernel 0: all 5 weight mats fp32 -> fp16 in one launch.
// ---------------------------------------------------------------------------
__global__ __launch_bounds__(256) void wconv_all(
    const float* __restrict__ W0, const float* __restrict__ W1,
    const float* __restrict__ W2, const float* __restrict__ W3,
    const float* __restrict__ W4, u16* __restrict__ wbuf) {
    int mat = blockIdx.y;
    const float* W = (mat == 0) ? W0 : (mat == 1) ? W1 : (mat == 2) ? W2
                   : (mat == 3) ? W3 : W4;
    u16* o = wbuf + (size_t)mat * WSZ;
    int i = (blockIdx.x * 256 + threadIdx.x) * 4;
    float4 w = *(const float4*)(W + i);
    ushort4 h;
    h.x = f16b(w.x);
    h.y = f16b(w.y);
    h.z = f16b(w.z);
    h.w = f16b(w.w);
    *(ushort4*)(o + i) = h;
}

// ---------------------------------------------------------------------------
// Kernel 1: LayerNorm, coalesced 16-token tile (R9, kept).
// ---------------------------------------------------------------------------
__global__ __launch_bounds__(256) void ln_kernel(const float* __restrict__ x,
                                                 const float* __restrict__ gamma,
                                                 const float* __restrict__ beta,
                                                 u16* __restrict__ xh) {
    int b = blockIdx.y;
    int t0 = blockIdx.x * 16;
    int tid = threadIdx.x;
    int tx = tid & 15;          // t offset
    int cg = tid >> 4;          // c group 0..15
    const float* xb = x + (size_t)b * C_ * T_ + t0 + tx;

    float v[48];
    float s = 0.f, sq = 0.f;
    #pragma unroll
    for (int i = 0; i < 48; ++i) {
        float val = xb[(size_t)(i * 16 + cg) * T_];
        v[i] = val; s += val; sq += val * val;
    }
    __shared__ float rs_[16][16], rq_[16][16];   // [cg][tx]
    rs_[cg][tx] = s;
    rq_[cg][tx] = sq;
    __syncthreads();
    __shared__ float mu_[16], rstd_[16];
    if (tid < 16) {
        float S = 0.f, Q = 0.f;
        #pragma unroll
        for (int k = 0; k < 16; ++k) { S += rs_[k][tid]; Q += rq_[k][tid]; }
        float mu = S * (1.0f / 768.0f);
        float var = Q * (1.0f / 768.0f) - mu * mu;
        mu_[tid] = mu;
        rstd_[tid] = 1.0f / sqrtf(var + 1e-5f);
    }
    __syncthreads();
    float mu = mu_[tx], rstd = rstd_[tx];
    __shared__ u16 Lt[16][776];                  // +8 u16 pad
    #pragma unroll
    for (int i = 0; i < 48; ++i) {
        int c = i * 16 + cg;
        Lt[tx][c] = f16b((v[i] - mu) * rstd * gamma[c] + beta[c]);
    }
    __syncthreads();
    size_t obase = ((size_t)b * 1024 + t0) * C_;
    #pragma unroll
    for (int st = 0; st < 12; ++st) {
        int idx = st * 256 + tid;
        int t = idx / 192, c4 = idx % 192;
        *(ushort4*)(xh + obase + (size_t)t * C_ + c4 * 4) = *(ushort4*)&Lt[t][c4 * 4];
    }
}

// ---------------------------------------------------------------------------
// Kernel 2: fused QKVG GEMM, fp16 MFMA. R14: R12's gld_lds pipeline (90.4us,
// the proven floor of the 6-variant schedule ledger) deepened to 3 buffers
// with COUNTED vmcnt (T4, m218): bottom-of-loop is
//   s_waitcnt vmcnt(4); s_barrier    (raw, no drain)
// so tile t+2's 4 loads stay in flight ACROSS the barrier -- each tile gets
// ~2 compute phases to land instead of <1 (R12's __syncthreads = vmcnt(0)
// drained the just-issued t+1 loads every iter).
// Invariant (per-wave FIFO vmcnt): at iter t's wait, outstanding =
// {t+1:4, t+2:4}; vmcnt(4) retires the oldest 4 = t+1's for this wave;
// barrier => all waves did so => tile t+1 fully in LDS before any read.
// Buffer t%3: full barrier epoch between last-read and next-write (WAR ok).
// Loop VMEM ops are gld_lds ONLY (fragment reads are lgkmcnt) => counts exact.
// LDS 48KB x 3 blocks = 144 <= 160KB.
// ---------------------------------------------------------------------------
__global__ __launch_bounds__(256, 3) void qkvg_mfma(
    const u16* __restrict__ xh, const u16* __restrict__ wmats,
    const float* __restrict__ bq, const float* __restrict__ bk,
    const float* __restrict__ bv, const float* __restrict__ bg,
    u16* __restrict__ qh, u16* __restrict__ kh,
    u16* __restrict__ vth, u16* __restrict__ g) {
    int bx = blockIdx.x;            // m tile 0..63
    int by = blockIdx.y;            // 0..23
    int mat = by / 6;
    int n0  = (by % 6) * 128;
    int m0  = bx * 128;
    const u16* Wh = wmats + (size_t)mat * WSZ;
    const float* bias = (mat == 0) ? bq : (mat == 1) ? bk : (mat == 2) ? bv : bg;

    __shared__ __attribute__((aligned(16))) u16 Ah[3 * 4096], Bh[3 * 4096];  // 48 KB

    int tid  = threadIdx.x;
    int lane = tid & 63, wid = tid >> 6;
    int wm = (wid & 1) * 64, wn = (wid >> 1) * 64;
    int fr = lane & 15, rq = (lane >> 4) * 4;

    f32x4 acc[4][4];
    #pragma unroll
    for (int i = 0; i < 4; ++i)
        #pragma unroll
        for (int j = 0; j < 4; ++j)
            acc[i][j] = (f32x4){0.f, 0.f, 0.f, 0.f};

    int ba = (wm >> 4), bb2 = (wn >> 4);

    // gld_lds staging: wave wid owns fragment blocks f0, f0+1
    int f0 = 2 * wid;
    const u16* gA0 = xh + (size_t)(m0 + f0 * 16 + fr) * 768 + (lane >> 4) * 8;
    const u16* gA1 = gA0 + (size_t)16 * 768;
    const u16* gB0 = Wh + (size_t)(n0 + f0 * 16 + fr) * 768 + (lane >> 4) * 8;
    const u16* gB1 = gB0 + (size_t)16 * 768;
    int la0 = f0 * 512 + lane * 8;   // u16 units; = uniform base + lane*16B
    int la1 = la0 + 512;

    #define STAGE(T, BUF) do { int kk0 = (T) * 32; int bo_ = (BUF) * 4096; \
        gld16(gA0 + kk0, Ah + bo_ + la0); \
        gld16(gA1 + kk0, Ah + bo_ + la1); \
        gld16(gB0 + kk0, Bh + bo_ + la0); \
        gld16(gB1 + kk0, Bh + bo_ + la1); \
    } while (0)

    STAGE(0, 0);
    STAGE(1, 1);                       // 8 loads in flight
    asm volatile("s_waitcnt vmcnt(4)" ::: "memory");   // tile 0 landed (this wave)
    __builtin_amdgcn_s_barrier();                       // ... for all waves
    int cur = 0;
    for (int t = 0; t < 24; ++t) {
        int nx2 = cur + 2; if (nx2 >= 3) nx2 -= 3;
        if (t + 2 < 24) STAGE(t + 2, nx2);   // stays in flight across the barrier
        int cb = cur * 4096;
        f16x8 fah[4], fbh[4];
        #pragma unroll
        for (int i = 0; i < 4; ++i) {
            fah[i] = *(const f16x8*)(Ah + cb + (ba + i) * 512 + lane * 8);
            fbh[i] = *(const f16x8*)(Bh + cb + (bb2 + i) * 512 + lane * 8);
        }
        if (mat == 2) {   // v: swapped operands -> transposed (token-minor) store
            #pragma unroll
            for (int mi = 0; mi < 4; ++mi)
                #pragma unroll
                for (int ni = 0; ni < 4; ++ni)
                    acc[mi][ni] = __builtin_amdgcn_mfma_f32_16x16x32_f16(fbh[ni], fah[mi], acc[mi][ni], 0, 0, 0);
        } else {
            #pragma unroll
            for (int mi = 0; mi < 4; ++mi)
                #pragma unroll
                for (int ni = 0; ni < 4; ++ni)
                    acc[mi][ni] = __builtin_amdgcn_mfma_f32_16x16x32_f16(fah[mi], fbh[ni], acc[mi][ni], 0, 0, 0);
        }
        if (t < 22) {
            asm volatile("s_waitcnt vmcnt(4)" ::: "memory");   // t+1 landed
        } else {
            asm volatile("s_waitcnt vmcnt(0)" ::: "memory");   // tail drain
        }
        __builtin_amdgcn_s_barrier();
        cur = (cur == 2) ? 0 : cur + 1;
    }
    #undef STAGE
    // epilogue: C/D layout col=lane&15, row=(lane>>4)*4+reg
    if (mat == 2) {
        int bb = m0 >> 10;
        #pragma unroll
        for (int mi = 0; mi < 4; ++mi) {
            int tok = m0 + wm + mi * 16 + fr;
            int tl  = tok & 1023;
            #pragma unroll
            for (int ni = 0; ni < 4; ++ni) {
                #pragma unroll
                for (int rg = 0; rg < 4; ++rg) {
                    int ch = n0 + wn + ni * 16 + rq + rg;
                    float val = acc[mi][ni][rg] + bias[ch];
                    size_t addr = ((size_t)((bb * 12 + (ch >> 6)) * 64 + (ch & 63))) * 1024 + tl;
                    vth[addr] = f16b(val);
                }
            }
        }
    } else {
        u16* oh = (mat == 0) ? qh : (mat == 1) ? kh : g;
        float scale = (mat == 0) ? 0.125f : 1.0f;
        #pragma unroll
        for (int ni = 0; ni < 4; ++ni) {
            int col = n0 + wn + ni * 16 + fr;
            float bb = bias[col];
            #pragma unroll
            for (int mi = 0; mi < 4; ++mi) {
                int row = m0 + wm + mi * 16 + rq;
                #pragma unroll
                for (int rg = 0; rg < 4; ++rg) {
                    float val = (acc[mi][ni][rg] + bb) * scale;
                    oh[(size_t)(row + rg) * 768 + col] = f16b(val);
                }
            }
        }
    }
}

// ---------------------------------------------------------------------------
// Kernel 3: MFMA flash attention, fp16, swapped QK^T, QBLK=128,
// gld_lds K/V staging (R11/R12, unchanged).
// ---------------------------------------------------------------------------
__global__ __launch_bounds__(256, 3) void attn_mfma(
    const u16* __restrict__ qhg, const u16* __restrict__ khg,
    const u16* __restrict__ vthg, const u16* __restrict__ gbf,
    u16* __restrict__ yh) {
    int qt = blockIdx.x;   // 0..7 (128 q-rows)
    int h  = blockIdx.y;   // 0..11
    int b  = blockIdx.z;   // 0..7
    __shared__ __attribute__((aligned(16))) u16 Kh[2 * 4096], Vh[2 * 4096];
    __shared__ u16 Ps[64 * 72];
    int tid = threadIdx.x;
    int lane = tid & 63, w = tid >> 6;
    int fr = lane & 15, quad = lane >> 4, fq = quad * 8;

    size_t qbaseA = ((size_t)(b * 1024 + qt * 128)) * 768 + h * 64;
    size_t qbaseB = qbaseA + (size_t)64 * 768;
    size_t kbase = ((size_t)(b * 1024)) * 768 + h * 64;
    size_t vbase = ((size_t)((b * 12 + h) * 64)) * 1024;

    f16x8 aqA[2], aqB[2];
    #pragma unroll
    for (int kk = 0; kk < 2; ++kk) {
        size_t ro = (size_t)(w * 16 + fr) * 768 + kk * 32 + fq;
        aqA[kk] = *(const f16x8*)(qhg + qbaseA + ro);
        aqB[kk] = *(const f16x8*)(qhg + qbaseB + ro);
    }

    float m_A = -1e30f, l_A = 0.0f, m_B = -1e30f, l_B = 0.0f;
    f32x4 OA[4], OB[4];
    #pragma unroll
    for (int i = 0; i < 4; ++i) {
        OA[i] = (f32x4){0.f, 0.f, 0.f, 0.f};
        OB[i] = (f32x4){0.f, 0.f, 0.f, 0.f};
    }

    // gld_lds staging: wave w owns fragment blocks f0 = 2w, f0+1
    int f0 = 2 * w;
    int f1 = f0 + 1;
    const u16* kgA = khg + kbase + (size_t)((f0 & 3) * 16 + fr) * 768 + (f0 >> 2) * 32 + (lane >> 4) * 8;
    const u16* kgB = khg + kbase + (size_t)((f1 & 3) * 16 + fr) * 768 + (f1 >> 2) * 32 + (lane >> 4) * 8;
    const u16* vgA = vthg + vbase + (size_t)((f0 & 3) * 16 + fr) * 1024 + (f0 >> 2) * 32 + (lane >> 4) * 8;
    const u16* vgB = vthg + vbase + (size_t)((f1 & 3) * 16 + fr) * 1024 + (f1 >> 2) * 32 + (lane >> 4) * 8;
    int ldA = f0 * 512 + lane * 8;
    int ldB = ldA + 512;

    #define STAGE(ST, BUF) do { \
        size_t ko = (size_t)(ST) * 49152; \
        size_t vo = (size_t)(ST) * 64; \
        int bo_ = (BUF) * 4096; \
        gld16(kgA + ko, Kh + bo_ + ldA); \
        gld16(kgB + ko, Kh + bo_ + ldB); \
        gld16(vgA + vo, Vh + bo_ + ldA); \
        gld16(vgB + vo, Vh + bo_ + ldB); \
    } while (0)

    // one Q-strip against the staged K/V tile in buf[cur]
    #define STRIP(AQ, MS, LS, OACC) do { \
        f32x4 sacc[4]; \
        _Pragma("unroll") \
        for (int nt = 0; nt < 4; ++nt) sacc[nt] = (f32x4){0.f, 0.f, 0.f, 0.f}; \
        _Pragma("unroll") \
        for (int nt = 0; nt < 4; ++nt) \
            _Pragma("unroll") \
            for (int kk = 0; kk < 2; ++kk) { \
                f16x8 kb = *(const f16x8*)(Kh + cur * 4096 + (kk * 4 + nt) * 512 + lane * 8); \
                sacc[nt] = __builtin_amdgcn_mfma_f32_16x16x32_f16(kb, AQ[kk], sacc[nt], 0, 0, 0); \
            } \
        float mx = -1e30f; \
        _Pragma("unroll") \
        for (int nt = 0; nt < 4; ++nt) \
            _Pragma("unroll") \
            for (int rg = 0; rg < 4; ++rg) mx = fmaxf(mx, sacc[nt][rg]); \
        mx = fmaxf(mx, __shfl_xor(mx, 16)); \
        mx = fmaxf(mx, __shfl_xor(mx, 32)); \
        float mn = fmaxf(MS, mx); \
        float al = __expf(MS - mn); \
        MS = mn; \
        float rs = 0.0f; \
        _Pragma("unroll") \
        for (int nt = 0; nt < 4; ++nt) \
            _Pragma("unroll") \
            for (int rg = 0; rg < 4; ++rg) { \
                float p = __expf(sacc[nt][rg] - mn); \
                sacc[nt][rg] = p; \
                rs += p; \
            } \
        rs += __shfl_xor(rs, 16); \
        rs += __shfl_xor(rs, 32); \
        LS = LS * al + rs; \
        int prow = (w * 16 + fr) * 72; \
        _Pragma("unroll") \
        for (int nt = 0; nt < 4; ++nt) { \
            ushort4 hp; \
            hp.x = f16b(sacc[nt][0]); \
            hp.y = f16b(sacc[nt][1]); \
            hp.z = f16b(sacc[nt][2]); \
            hp.w = f16b(sacc[nt][3]); \
            *(ushort4*)&Ps[prow + nt * 16 + quad * 4] = hp; \
        } \
        float alr[4]; \
        _Pragma("unroll") \
        for (int rg = 0; rg < 4; ++rg) alr[rg] = __shfl(al, quad * 4 + rg, 16); \
        _Pragma("unroll") \
        for (int dn = 0; dn < 4; ++dn) \
            _Pragma("unroll") \
            for (int rg = 0; rg < 4; ++rg) OACC[dn][rg] *= alr[rg]; \
        _Pragma("unroll") \
        for (int kk = 0; kk < 2; ++kk) { \
            f16x8 pa = *(const f16x8*)&Ps[(w * 16 + fr) * 72 + fq + kk * 32]; \
            _Pragma("unroll") \
            for (int dn = 0; dn < 4; ++dn) { \
                f16x8 vb = *(const f16x8*)(Vh + cur * 4096 + (kk * 4 + dn) * 512 + lane * 8); \
                OACC[dn] = __builtin_amdgcn_mfma_f32_16x16x32_f16(pa, vb, OACC[dn], 0, 0, 0); \
            } \
        } \
    } while (0)

    STAGE(0, 0);
    __syncthreads();               // st0 staged (vmcnt drained by barrier)
    int cur = 0;
    for (int st = 0; st < 16; ++st) {
        int nxt = cur ^ 1;
        if (st + 1 < 16) STAGE(st + 1, nxt);   // issue; drains at bottom barrier
        STRIP(aqA, m_A, l_A, OA);
        STRIP(aqB, m_B, l_B, OB);
        __syncthreads();
        cur = nxt;
    }
    #undef STAGE
    #undef STRIP
    // epilogue: normalize, sigmoid gate, fp16 y store (both strips)
    float invA[4], invB[4];
    #pragma unroll
    for (int rg = 0; rg < 4; ++rg) {
        invA[rg] = 1.0f / __shfl(l_A, quad * 4 + rg, 16);
        invB[rg] = 1.0f / __shfl(l_B, quad * 4 + rg, 16);
    }
    int tokA0 = b * 1024 + qt * 128 + w * 16;
    #pragma unroll
    for (int dn = 0; dn < 4; ++dn) {
        int ch = h * 64 + dn * 16 + fr;
        #pragma unroll
        for (int rg = 0; rg < 4; ++rg) {
            int tok = tokA0 + quad * 4 + rg;
            float gv = f16f(gbf[(size_t)tok * 768 + ch]);
            float sg = 1.0f / (1.0f + __expf(-gv));
            yh[(size_t)tok * 768 + ch] = f16b(OA[dn][rg] * invA[rg] * sg);
            int tok2 = tok + 64;
            float gv2 = f16f(gbf[(size_t)tok2 * 768 + ch]);
            float sg2 = 1.0f / (1.0f + __expf(-gv2));
            yh[(size_t)tok2 * 768 + ch] = f16b(OB[dn][rg] * invB[rg] * sg2);
        }
    }
}

// ---------------------------------------------------------------------------
// Kernel 4: out = y @ Wo^T + bo -> (B, C, T). Exact R12 gld_lds DB form
// (proven; revert anchor).
// ---------------------------------------------------------------------------
__global__ __launch_bounds__(256, 3) void out_mfma(
    const u16* __restrict__ yh, const u16* __restrict__ woh,
    const float* __restrict__ bo, float* __restrict__ out) {
    int bx = blockIdx.x;   // c tile 0..5
    int by = blockIdx.y;   // t tile 0..63
    int m0 = bx * 128;     // c
    int n0 = by * 128;     // t

    __shared__ __attribute__((aligned(16))) u16 Ah[2 * 4096], Bh[2 * 4096];  // 32 KB

    int tid  = threadIdx.x;
    int lane = tid & 63, wid = tid >> 6;
    int wm = (wid & 1) * 64, wn = (wid >> 1) * 64;
    int fr = lane & 15, rq = (lane >> 4) * 4;

    f32x4 acc[4][4];
    #pragma unroll
    for (int i = 0; i < 4; ++i)
        #pragma unroll
        for (int j = 0; j < 4; ++j)
            acc[i][j] = (f32x4){0.f, 0.f, 0.f, 0.f};

    int ba = (wm >> 4), bb2 = (wn >> 4);

    int f0 = 2 * wid;
    const u16* gA0 = woh + (size_t)(m0 + f0 * 16 + fr) * 768 + (lane >> 4) * 8;
    const u16* gA1 = gA0 + (size_t)16 * 768;
    const u16* gB0 = yh + (size_t)(n0 + f0 * 16 + fr) * 768 + (lane >> 4) * 8;
    const u16* gB1 = gB0 + (size_t)16 * 768;
    int la0 = f0 * 512 + lane * 8;
    int la1 = la0 + 512;

    #define STAGE(T, BUF) do { int kk0 = (T) * 32; int bo_ = (BUF) * 4096; \
        gld16(gA0 + kk0, Ah + bo_ + la0); \
        gld16(gA1 + kk0, Ah + bo_ + la1); \
        gld16(gB0 + kk0, Bh + bo_ + la0); \
        gld16(gB1 + kk0, Bh + bo_ + la1); \
    } while (0)

    STAGE(0, 0);
    __syncthreads();
    int cur = 0;
    for (int t = 0; t < 24; ++t) {
        int nxt = cur ^ 1;
        if (t + 1 < 24) STAGE(t + 1, nxt);
        int cb = cur * 4096;
        f16x8 fah[4], fbh[4];
        #pragma unroll
        for (int i = 0; i < 4; ++i) {
            fah[i] = *(const f16x8*)(Ah + cb + (ba + i) * 512 + lane * 8);
            fbh[i] = *(const f16x8*)(Bh + cb + (bb2 + i) * 512 + lane * 8);
        }
        #pragma unroll
        for (int mi = 0; mi < 4; ++mi)
            #pragma unroll
            for (int ni = 0; ni < 4; ++ni)
                acc[mi][ni] = __builtin_amdgcn_mfma_f32_16x16x32_f16(fah[mi], fbh[ni], acc[mi][ni], 0, 0, 0);
        __syncthreads();
        cur = nxt;
    }
    #undef STAGE
    int bb = n0 >> 10;
    #pragma unroll
    for (int ni = 0; ni < 4; ++ni) {
        int colg = n0 + wn + ni * 16 + fr;
        int tl = colg & 1023;
        #pragma unroll
        for (int mi = 0; mi < 4; ++mi) {
            int row = m0 + wm + mi * 16 + rq;
            #pragma unroll
            for (int rg = 0; rg < 4; ++rg) {
                float val = acc[mi][ni][rg] + bo[row + rg];
                out[((size_t)bb * 768 + row + rg) * 1024 + tl] = val;
            }
        }
    }
}

extern "C" void kernel_launch(void* const* d_in, const int* in_sizes, int n_in,
                              void* d_out, int out_size, void* d_ws, size_t ws_size,
                              hipStream_t stream) {
    const float* x     = (const float*)d_in[0];
    const float* Wq    = (const float*)d_in[1];
    const float* bq    = (const float*)d_in[2];
    const float* Wk    = (const float*)d_in[3];
    const float* bk    = (const float*)d_in[4];
    const float* Wv    = (const float*)d_in[5];
    const float* bv    = (const float*)d_in[6];
    const float* Wo    = (const float*)d_in[7];
    const float* bo    = (const float*)d_in[8];
    const float* Wg    = (const float*)d_in[9];
    const float* bg    = (const float*)d_in[10];
    const float* gamma = (const float*)d_in[11];
    const float* beta  = (const float*)d_in[12];
    float* out = (float*)d_out;

    // workspace (ushort, all fp16): xn|q|k|vt|g | wbuf[Wq,Wk,Wv,Wg,Wo]
    const size_t S = (size_t)BT_ * C_;
    u16* xn   = (u16*)d_ws;
    u16* qh   = xn + S;
    u16* kh   = qh + S;
    u16* vth  = kh + S;
    u16* g_bf = vth + S;
    u16* wbuf = g_bf + S;
    u16* y_h  = xn;          // alias: xn dead after qkvg

    wconv_all<<<dim3(WSZ / 1024, 5), 256, 0, stream>>>(Wq, Wk, Wv, Wg, Wo, wbuf);
    ln_kernel<<<dim3(64, 8), 256, 0, stream>>>(x, gamma, beta, xn);
    qkvg_mfma<<<dim3(64, 24), 256, 0, stream>>>(xn, wbuf, bq, bk, bv, bg,
                                                qh, kh, vth, g_bf);
    attn_mfma<<<dim3(8, 12, 8), 256, 0, stream>>>(qh, kh, vth, g_bf, y_h);
    out_mfma<<<dim3(6, 64), 256, 0, stream>>>(y_h, wbuf + (size_t)4 * WSZ, bo, out);
}

// Round 15
// 273.282 us; speedup vs baseline: 1.2794x; 1.0252x over previous
//
#include <hip/hip_runtime.h>
#include <math.h>

#define B_   8
#define C_   768
#define T_   1024
#define BT_  (B_*T_)       // 8192
#define WSZ  (C_*C_)       // 589824 per weight matrix

using f16x8 = __attribute__((ext_vector_type(8))) _Float16;
using f32x4 = __attribute__((ext_vector_type(4))) float;
typedef unsigned short u16;

// ---- fp16 helpers ----
__device__ inline u16 f16b(float x) {
    _Float16 h = (_Float16)x;
    return __builtin_bit_cast(u16, h);
}
__device__ inline float f16f(u16 b) {
    return (float)__builtin_bit_cast(_Float16, b);
}

// Direct global->LDS DMA, 16B/lane. HW: dest = readfirstlane(ptr) + lane*16.
// Callers pass lds = base + lane*8 (u16), base wave-uniform. (R3/R11/R12-verified.)
typedef const __attribute__((address_space(1))) unsigned int gas_uint;
typedef __attribute__((address_space(3))) unsigned int las_uint;
__device__ inline void gld16(const u16* __restrict__ g, u16* l) {
    __builtin_amdgcn_global_load_lds((gas_uint*)g, (las_uint*)l, 16, 0, 0);
}

// ---------------------------------------------------------------------------
// Kernel 0: all 5 weight mats fp32 -> fp16 in one launch.
// ---------------------------------------------------------------------------
__global__ __launch_bounds__(256) void wconv_all(
    const float* __restrict__ W0, const float* __restrict__ W1,
    const float* __restrict__ W2, const float* __restrict__ W3,
    const float* __restrict__ W4, u16* __restrict__ wbuf) {
    int mat = blockIdx.y;
    const float* W = (mat == 0) ? W0 : (mat == 1) ? W1 : (mat == 2) ? W2
                   : (mat == 3) ? W3 : W4;
    u16* o = wbuf + (size_t)mat * WSZ;
    int i = (blockIdx.x * 256 + threadIdx.x) * 4;
    float4 w = *(const float4*)(W + i);
    ushort4 h;
    h.x = f16b(w.x);
    h.y = f16b(w.y);
    h.z = f16b(w.z);
    h.w = f16b(w.w);
    *(ushort4*)(o + i) = h;
}

// ---------------------------------------------------------------------------
// Kernel 1: LayerNorm, coalesced 16-token tile (R9, kept).
// ---------------------------------------------------------------------------
__global__ __launch_bounds__(256) void ln_kernel(const float* __restrict__ x,
                                                 const float* __restrict__ gamma,
                                                 const float* __restrict__ beta,
                                                 u16* __restrict__ xh) {
    int b = blockIdx.y;
    int t0 = blockIdx.x * 16;
    int tid = threadIdx.x;
    int tx = tid & 15;          // t offset
    int cg = tid >> 4;          // c group 0..15
    const float* xb = x + (size_t)b * C_ * T_ + t0 + tx;

    float v[48];
    float s = 0.f, sq = 0.f;
    #pragma unroll
    for (int i = 0; i < 48; ++i) {
        float val = xb[(size_t)(i * 16 + cg) * T_];
        v[i] = val; s += val; sq += val * val;
    }
    __shared__ float rs_[16][16], rq_[16][16];   // [cg][tx]
    rs_[cg][tx] = s;
    rq_[cg][tx] = sq;
    __syncthreads();
    __shared__ float mu_[16], rstd_[16];
    if (tid < 16) {
        float S = 0.f, Q = 0.f;
        #pragma unroll
        for (int k = 0; k < 16; ++k) { S += rs_[k][tid]; Q += rq_[k][tid]; }
        float mu = S * (1.0f / 768.0f);
        float var = Q * (1.0f / 768.0f) - mu * mu;
        mu_[tid] = mu;
        rstd_[tid] = 1.0f / sqrtf(var + 1e-5f);
    }
    __syncthreads();
    float mu = mu_[tx], rstd = rstd_[tx];
    __shared__ u16 Lt[16][776];                  // +8 u16 pad
    #pragma unroll
    for (int i = 0; i < 48; ++i) {
        int c = i * 16 + cg;
        Lt[tx][c] = f16b((v[i] - mu) * rstd * gamma[c] + beta[c]);
    }
    __syncthreads();
    size_t obase = ((size_t)b * 1024 + t0) * C_;
    #pragma unroll
    for (int st = 0; st < 12; ++st) {
        int idx = st * 256 + tid;
        int t = idx / 192, c4 = idx % 192;
        *(ushort4*)(xh + obase + (size_t)t * C_ + c4 * 4) = *(ushort4*)&Lt[t][c4 * 4];
    }
}

// ---------------------------------------------------------------------------
// Kernel 2: fused QKVG GEMM, fp16 MFMA. R15: EXACT R12 form -- the measured
// floor of the 8-variant schedule ledger (90.4us): 2-buffer gld_lds DB,
// issue(t+1) -> compute(t) -> __syncthreads (drain). R14's 3-buffer counted
// vmcnt regressed to 96us (inline-asm waits pinned scheduling, VALU +10pp).
// qkvg is CLOSED at this structure.
// ---------------------------------------------------------------------------
__global__ __launch_bounds__(256, 3) void qkvg_mfma(
    const u16* __restrict__ xh, const u16* __restrict__ wmats,
    const float* __restrict__ bq, const float* __restrict__ bk,
    const float* __restrict__ bv, const float* __restrict__ bg,
    u16* __restrict__ qh, u16* __restrict__ kh,
    u16* __restrict__ vth, u16* __restrict__ g) {
    int bx = blockIdx.x;            // m tile 0..63
    int by = blockIdx.y;            // 0..23
    int mat = by / 6;
    int n0  = (by % 6) * 128;
    int m0  = bx * 128;
    const u16* Wh = wmats + (size_t)mat * WSZ;
    const float* bias = (mat == 0) ? bq : (mat == 1) ? bk : (mat == 2) ? bv : bg;

    __shared__ __attribute__((aligned(16))) u16 Ah[2 * 4096], Bh[2 * 4096];  // 32 KB

    int tid  = threadIdx.x;
    int lane = tid & 63, wid = tid >> 6;
    int wm = (wid & 1) * 64, wn = (wid >> 1) * 64;
    int fr = lane & 15, rq = (lane >> 4) * 4;

    f32x4 acc[4][4];
    #pragma unroll
    for (int i = 0; i < 4; ++i)
        #pragma unroll
        for (int j = 0; j < 4; ++j)
            acc[i][j] = (f32x4){0.f, 0.f, 0.f, 0.f};

    int ba = (wm >> 4), bb2 = (wn >> 4);

    // gld_lds staging: wave wid owns fragment blocks f0, f0+1
    int f0 = 2 * wid;
    const u16* gA0 = xh + (size_t)(m0 + f0 * 16 + fr) * 768 + (lane >> 4) * 8;
    const u16* gA1 = gA0 + (size_t)16 * 768;
    const u16* gB0 = Wh + (size_t)(n0 + f0 * 16 + fr) * 768 + (lane >> 4) * 8;
    const u16* gB1 = gB0 + (size_t)16 * 768;
    int la0 = f0 * 512 + lane * 8;   // u16 units; = uniform base + lane*16B
    int la1 = la0 + 512;

    #define STAGE(T, BUF) do { int kk0 = (T) * 32; int bo_ = (BUF) * 4096; \
        gld16(gA0 + kk0, Ah + bo_ + la0); \
        gld16(gA1 + kk0, Ah + bo_ + la1); \
        gld16(gB0 + kk0, Bh + bo_ + la0); \
        gld16(gB1 + kk0, Bh + bo_ + la1); \
    } while (0)

    STAGE(0, 0);
    __syncthreads();               // tile 0 staged (vmcnt drained by barrier)
    int cur = 0;
    for (int t = 0; t < 24; ++t) {
        int nxt = cur ^ 1;
        if (t + 1 < 24) STAGE(t + 1, nxt);   // issue; drains at bottom barrier
        int cb = cur * 4096;
        f16x8 fah[4], fbh[4];
        #pragma unroll
        for (int i = 0; i < 4; ++i) {
            fah[i] = *(const f16x8*)(Ah + cb + (ba + i) * 512 + lane * 8);
            fbh[i] = *(const f16x8*)(Bh + cb + (bb2 + i) * 512 + lane * 8);
        }
        if (mat == 2) {   // v: swapped operands -> transposed (token-minor) store
            #pragma unroll
            for (int mi = 0; mi < 4; ++mi)
                #pragma unroll
                for (int ni = 0; ni < 4; ++ni)
                    acc[mi][ni] = __builtin_amdgcn_mfma_f32_16x16x32_f16(fbh[ni], fah[mi], acc[mi][ni], 0, 0, 0);
        } else {
            #pragma unroll
            for (int mi = 0; mi < 4; ++mi)
                #pragma unroll
                for (int ni = 0; ni < 4; ++ni)
                    acc[mi][ni] = __builtin_amdgcn_mfma_f32_16x16x32_f16(fah[mi], fbh[ni], acc[mi][ni], 0, 0, 0);
        }
        __syncthreads();
        cur = nxt;
    }
    #undef STAGE
    // epilogue: C/D layout col=lane&15, row=(lane>>4)*4+reg
    if (mat == 2) {
        int bb = m0 >> 10;
        #pragma unroll
        for (int mi = 0; mi < 4; ++mi) {
            int tok = m0 + wm + mi * 16 + fr;
            int tl  = tok & 1023;
            #pragma unroll
            for (int ni = 0; ni < 4; ++ni) {
                #pragma unroll
                for (int rg = 0; rg < 4; ++rg) {
                    int ch = n0 + wn + ni * 16 + rq + rg;
                    float val = acc[mi][ni][rg] + bias[ch];
                    size_t addr = ((size_t)((bb * 12 + (ch >> 6)) * 64 + (ch & 63))) * 1024 + tl;
                    vth[addr] = f16b(val);
                }
            }
        }
    } else {
        u16* oh = (mat == 0) ? qh : (mat == 1) ? kh : g;
        float scale = (mat == 0) ? 0.125f : 1.0f;
        #pragma unroll
        for (int ni = 0; ni < 4; ++ni) {
            int col = n0 + wn + ni * 16 + fr;
            float bb = bias[col];
            #pragma unroll
            for (int mi = 0; mi < 4; ++mi) {
                int row = m0 + wm + mi * 16 + rq;
                #pragma unroll
                for (int rg = 0; rg < 4; ++rg) {
                    float val = (acc[mi][ni][rg] + bb) * scale;
                    oh[(size_t)(row + rg) * 768 + col] = f16b(val);
                }
            }
        }
    }
}

// ---------------------------------------------------------------------------
// Kernel 3: MFMA flash attention, fp16, swapped QK^T, QBLK=128, gld_lds K/V
// staging. R15: + s_setprio(1) around MFMA clusters (T5, m191: +4-7% on
// attn with desynchronized blocks -- ours run 3/CU at different st phases).
// Softmax VALU runs at prio 0. Pure scheduler hint, zero correctness surface.
// ---------------------------------------------------------------------------
__global__ __launch_bounds__(256, 3) void attn_mfma(
    const u16* __restrict__ qhg, const u16* __restrict__ khg,
    const u16* __restrict__ vthg, const u16* __restrict__ gbf,
    u16* __restrict__ yh) {
    int qt = blockIdx.x;   // 0..7 (128 q-rows)
    int h  = blockIdx.y;   // 0..11
    int b  = blockIdx.z;   // 0..7
    __shared__ __attribute__((aligned(16))) u16 Kh[2 * 4096], Vh[2 * 4096];
    __shared__ u16 Ps[64 * 72];
    int tid = threadIdx.x;
    int lane = tid & 63, w = tid >> 6;
    int fr = lane & 15, quad = lane >> 4, fq = quad * 8;

    size_t qbaseA = ((size_t)(b * 1024 + qt * 128)) * 768 + h * 64;
    size_t qbaseB = qbaseA + (size_t)64 * 768;
    size_t kbase = ((size_t)(b * 1024)) * 768 + h * 64;
    size_t vbase = ((size_t)((b * 12 + h) * 64)) * 1024;

    f16x8 aqA[2], aqB[2];
    #pragma unroll
    for (int kk = 0; kk < 2; ++kk) {
        size_t ro = (size_t)(w * 16 + fr) * 768 + kk * 32 + fq;
        aqA[kk] = *(const f16x8*)(qhg + qbaseA + ro);
        aqB[kk] = *(const f16x8*)(qhg + qbaseB + ro);
    }

    float m_A = -1e30f, l_A = 0.0f, m_B = -1e30f, l_B = 0.0f;
    f32x4 OA[4], OB[4];
    #pragma unroll
    for (int i = 0; i < 4; ++i) {
        OA[i] = (f32x4){0.f, 0.f, 0.f, 0.f};
        OB[i] = (f32x4){0.f, 0.f, 0.f, 0.f};
    }

    // gld_lds staging: wave w owns fragment blocks f0 = 2w, f0+1
    int f0 = 2 * w;
    int f1 = f0 + 1;
    const u16* kgA = khg + kbase + (size_t)((f0 & 3) * 16 + fr) * 768 + (f0 >> 2) * 32 + (lane >> 4) * 8;
    const u16* kgB = khg + kbase + (size_t)((f1 & 3) * 16 + fr) * 768 + (f1 >> 2) * 32 + (lane >> 4) * 8;
    const u16* vgA = vthg + vbase + (size_t)((f0 & 3) * 16 + fr) * 1024 + (f0 >> 2) * 32 + (lane >> 4) * 8;
    const u16* vgB = vthg + vbase + (size_t)((f1 & 3) * 16 + fr) * 1024 + (f1 >> 2) * 32 + (lane >> 4) * 8;
    int ldA = f0 * 512 + lane * 8;
    int ldB = ldA + 512;

    #define STAGE(ST, BUF) do { \
        size_t ko = (size_t)(ST) * 49152; \
        size_t vo = (size_t)(ST) * 64; \
        int bo_ = (BUF) * 4096; \
        gld16(kgA + ko, Kh + bo_ + ldA); \
        gld16(kgB + ko, Kh + bo_ + ldB); \
        gld16(vgA + vo, Vh + bo_ + ldA); \
        gld16(vgB + vo, Vh + bo_ + ldB); \
    } while (0)

    // one Q-strip against the staged K/V tile in buf[cur]
    #define STRIP(AQ, MS, LS, OACC) do { \
        f32x4 sacc[4]; \
        _Pragma("unroll") \
        for (int nt = 0; nt < 4; ++nt) sacc[nt] = (f32x4){0.f, 0.f, 0.f, 0.f}; \
        __builtin_amdgcn_s_setprio(1); \
        _Pragma("unroll") \
        for (int nt = 0; nt < 4; ++nt) \
            _Pragma("unroll") \
            for (int kk = 0; kk < 2; ++kk) { \
                f16x8 kb = *(const f16x8*)(Kh + cur * 4096 + (kk * 4 + nt) * 512 + lane * 8); \
                sacc[nt] = __builtin_amdgcn_mfma_f32_16x16x32_f16(kb, AQ[kk], sacc[nt], 0, 0, 0); \
            } \
        __builtin_amdgcn_s_setprio(0); \
        float mx = -1e30f; \
        _Pragma("unroll") \
        for (int nt = 0; nt < 4; ++nt) \
            _Pragma("unroll") \
            for (int rg = 0; rg < 4; ++rg) mx = fmaxf(mx, sacc[nt][rg]); \
        mx = fmaxf(mx, __shfl_xor(mx, 16)); \
        mx = fmaxf(mx, __shfl_xor(mx, 32)); \
        float mn = fmaxf(MS, mx); \
        float al = __expf(MS - mn); \
        MS = mn; \
        float rs = 0.0f; \
        _Pragma("unroll") \
        for (int nt = 0; nt < 4; ++nt) \
            _Pragma("unroll") \
            for (int rg = 0; rg < 4; ++rg) { \
                float p = __expf(sacc[nt][rg] - mn); \
                sacc[nt][rg] = p; \
                rs += p; \
            } \
        rs += __shfl_xor(rs, 16); \
        rs += __shfl_xor(rs, 32); \
        LS = LS * al + rs; \
        int prow = (w * 16 + fr) * 72; \
        _Pragma("unroll") \
        for (int nt = 0; nt < 4; ++nt) { \
            ushort4 hp; \
            hp.x = f16b(sacc[nt][0]); \
            hp.y = f16b(sacc[nt][1]); \
            hp.z = f16b(sacc[nt][2]); \
            hp.w = f16b(sacc[nt][3]); \
            *(ushort4*)&Ps[prow + nt * 16 + quad * 4] = hp; \
        } \
        float alr[4]; \
        _Pragma("unroll") \
        for (int rg = 0; rg < 4; ++rg) alr[rg] = __shfl(al, quad * 4 + rg, 16); \
        _Pragma("unroll") \
        for (int dn = 0; dn < 4; ++dn) \
            _Pragma("unroll") \
            for (int rg = 0; rg < 4; ++rg) OACC[dn][rg] *= alr[rg]; \
        __builtin_amdgcn_s_setprio(1); \
        _Pragma("unroll") \
        for (int kk = 0; kk < 2; ++kk) { \
            f16x8 pa = *(const f16x8*)&Ps[(w * 16 + fr) * 72 + fq + kk * 32]; \
            _Pragma("unroll") \
            for (int dn = 0; dn < 4; ++dn) { \
                f16x8 vb = *(const f16x8*)(Vh + cur * 4096 + (kk * 4 + dn) * 512 + lane * 8); \
                OACC[dn] = __builtin_amdgcn_mfma_f32_16x16x32_f16(pa, vb, OACC[dn], 0, 0, 0); \
            } \
        } \
        __builtin_amdgcn_s_setprio(0); \
    } while (0)

    STAGE(0, 0);
    __syncthreads();               // st0 staged (vmcnt drained by barrier)
    int cur = 0;
    for (int st = 0; st < 16; ++st) {
        int nxt = cur ^ 1;
        if (st + 1 < 16) STAGE(st + 1, nxt);   // issue; drains at bottom barrier
        STRIP(aqA, m_A, l_A, OA);
        STRIP(aqB, m_B, l_B, OB);
        __syncthreads();
        cur = nxt;
    }
    #undef STAGE
    #undef STRIP
    // epilogue: normalize, sigmoid gate, fp16 y store (both strips)
    float invA[4], invB[4];
    #pragma unroll
    for (int rg = 0; rg < 4; ++rg) {
        invA[rg] = 1.0f / __shfl(l_A, quad * 4 + rg, 16);
        invB[rg] = 1.0f / __shfl(l_B, quad * 4 + rg, 16);
    }
    int tokA0 = b * 1024 + qt * 128 + w * 16;
    #pragma unroll
    for (int dn = 0; dn < 4; ++dn) {
        int ch = h * 64 + dn * 16 + fr;
        #pragma unroll
        for (int rg = 0; rg < 4; ++rg) {
            int tok = tokA0 + quad * 4 + rg;
            float gv = f16f(gbf[(size_t)tok * 768 + ch]);
            float sg = 1.0f / (1.0f + __expf(-gv));
            yh[(size_t)tok * 768 + ch] = f16b(OA[dn][rg] * invA[rg] * sg);
            int tok2 = tok + 64;
            float gv2 = f16f(gbf[(size_t)tok2 * 768 + ch]);
            float sg2 = 1.0f / (1.0f + __expf(-gv2));
            yh[(size_t)tok2 * 768 + ch] = f16b(OB[dn][rg] * invB[rg] * sg2);
        }
    }
}

// ---------------------------------------------------------------------------
// Kernel 4: out = y @ Wo^T + bo -> (B, C, T). Exact R12 gld_lds DB form.
// ---------------------------------------------------------------------------
__global__ __launch_bounds__(256, 3) void out_mfma(
    const u16* __restrict__ yh, const u16* __restrict__ woh,
    const float* __restrict__ bo, float* __restrict__ out) {
    int bx = blockIdx.x;   // c tile 0..5
    int by = blockIdx.y;   // t tile 0..63
    int m0 = bx * 128;     // c
    int n0 = by * 128;     // t

    __shared__ __attribute__((aligned(16))) u16 Ah[2 * 4096], Bh[2 * 4096];  // 32 KB

    int tid  = threadIdx.x;
    int lane = tid & 63, wid = tid >> 6;
    int wm = (wid & 1) * 64, wn = (wid >> 1) * 64;
    int fr = lane & 15, rq = (lane >> 4) * 4;

    f32x4 acc[4][4];
    #pragma unroll
    for (int i = 0; i < 4; ++i)
        #pragma unroll
        for (int j = 0; j < 4; ++j)
            acc[i][j] = (f32x4){0.f, 0.f, 0.f, 0.f};

    int ba = (wm >> 4), bb2 = (wn >> 4);

    int f0 = 2 * wid;
    const u16* gA0 = woh + (size_t)(m0 + f0 * 16 + fr) * 768 + (lane >> 4) * 8;
    const u16* gA1 = gA0 + (size_t)16 * 768;
    const u16* gB0 = yh + (size_t)(n0 + f0 * 16 + fr) * 768 + (lane >> 4) * 8;
    const u16* gB1 = gB0 + (size_t)16 * 768;
    int la0 = f0 * 512 + lane * 8;
    int la1 = la0 + 512;

    #define STAGE(T, BUF) do { int kk0 = (T) * 32; int bo_ = (BUF) * 4096; \
        gld16(gA0 + kk0, Ah + bo_ + la0); \
        gld16(gA1 + kk0, Ah + bo_ + la1); \
        gld16(gB0 + kk0, Bh + bo_ + la0); \
        gld16(gB1 + kk0, Bh + bo_ + la1); \
    } while (0)

    STAGE(0, 0);
    __syncthreads();
    int cur = 0;
    for (int t = 0; t < 24; ++t) {
        int nxt = cur ^ 1;
        if (t + 1 < 24) STAGE(t + 1, nxt);
        int cb = cur * 4096;
        f16x8 fah[4], fbh[4];
        #pragma unroll
        for (int i = 0; i < 4; ++i) {
            fah[i] = *(const f16x8*)(Ah + cb + (ba + i) * 512 + lane * 8);
            fbh[i] = *(const f16x8*)(Bh + cb + (bb2 + i) * 512 + lane * 8);
        }
        #pragma unroll
        for (int mi = 0; mi < 4; ++mi)
            #pragma unroll
            for (int ni = 0; ni < 4; ++ni)
                acc[mi][ni] = __builtin_amdgcn_mfma_f32_16x16x32_f16(fah[mi], fbh[ni], acc[mi][ni], 0, 0, 0);
        __syncthreads();
        cur = nxt;
    }
    #undef STAGE
    int bb = n0 >> 10;
    #pragma unroll
    for (int ni = 0; ni < 4; ++ni) {
        int colg = n0 + wn + ni * 16 + fr;
        int tl = colg & 1023;
        #pragma unroll
        for (int mi = 0; mi < 4; ++mi) {
            int row = m0 + wm + mi * 16 + rq;
            #pragma unroll
            for (int rg = 0; rg < 4; ++rg) {
                float val = acc[mi][ni][rg] + bo[row + rg];
                out[((size_t)bb * 768 + row + rg) * 1024 + tl] = val;
            }
        }
    }
}

extern "C" void kernel_launch(void* const* d_in, const int* in_sizes, int n_in,
                              void* d_out, int out_size, void* d_ws, size_t ws_size,
                              hipStream_t stream) {
    const float* x     = (const float*)d_in[0];
    const float* Wq    = (const float*)d_in[1];
    const float* bq    = (const float*)d_in[2];
    const float* Wk    = (const float*)d_in[3];
    const float* bk    = (const float*)d_in[4];
    const float* Wv    = (const float*)d_in[5];
    const float* bv    = (const float*)d_in[6];
    const float* Wo    = (const float*)d_in[7];
    const float* bo    = (const float*)d_in[8];
    const float* Wg    = (const float*)d_in[9];
    const float* bg    = (const float*)d_in[10];
    const float* gamma = (const float*)d_in[11];
    const float* beta  = (const float*)d_in[12];
    float* out = (float*)d_out;

    // workspace (ushort, all fp16): xn|q|k|vt|g | wbuf[Wq,Wk,Wv,Wg,Wo]
    const size_t S = (size_t)BT_ * C_;
    u16* xn   = (u16*)d_ws;
    u16* qh   = xn + S;
    u16* kh   = qh + S;
    u16* vth  = kh + S;
    u16* g_bf = vth + S;
    u16* wbuf = g_bf + S;
    u16* y_h  = xn;          // alias: xn dead after qkvg

    wconv_all<<<dim3(WSZ / 1024, 5), 256, 0, stream>>>(Wq, Wk, Wv, Wg, Wo, wbuf);
    ln_kernel<<<dim3(64, 8), 256, 0, stream>>>(x, gamma, beta, xn);
    qkvg_mfma<<<dim3(64, 24), 256, 0, stream>>>(xn, wbuf, bq, bk, bv, bg,
                                                qh, kh, vth, g_bf);
    attn_mfma<<<dim3(8, 12, 8), 256, 0, stream>>>(qh, kh, vth, g_bf, y_h);
    out_mfma<<<dim3(6, 64), 256, 0, stream>>>(y_h, wbuf + (size_t)4 * WSZ, bo, out);
}

// Round 16
// 272.897 us; speedup vs baseline: 1.2812x; 1.0014x over previous
//
#include <hip/hip_runtime.h>
#include <math.h>

#define B_   8
#define C_   768
#define T_   1024
#define BT_  (B_*T_)       // 8192
#define WSZ  (C_*C_)       // 589824 per weight matrix

using f16x8 = __attribute__((ext_vector_type(8))) _Float16;
using f32x4 = __attribute__((ext_vector_type(4))) float;
typedef unsigned short u16;

// ---- fp16 helpers ----
__device__ inline u16 f16b(float x) {
    _Float16 h = (_Float16)x;
    return __builtin_bit_cast(u16, h);
}
__device__ inline float f16f(u16 b) {
    return (float)__builtin_bit_cast(_Float16, b);
}

// Direct global->LDS DMA, 16B/lane. HW: dest = readfirstlane(ptr) + lane*16.
// Callers pass lds = base + lane*8 (u16), base wave-uniform. (R3/R11/R12-verified.)
typedef const __attribute__((address_space(1))) unsigned int gas_uint;
typedef __attribute__((address_space(3))) unsigned int las_uint;
__device__ inline void gld16(const u16* __restrict__ g, u16* l) {
    __builtin_amdgcn_global_load_lds((gas_uint*)g, (las_uint*)l, 16, 0, 0);
}

// ---------------------------------------------------------------------------
// Kernel 0: all 5 weight mats fp32 -> fp16 in one launch.
// ---------------------------------------------------------------------------
__global__ __launch_bounds__(256) void wconv_all(
    const float* __restrict__ W0, const float* __restrict__ W1,
    const float* __restrict__ W2, const float* __restrict__ W3,
    const float* __restrict__ W4, u16* __restrict__ wbuf) {
    int mat = blockIdx.y;
    const float* W = (mat == 0) ? W0 : (mat == 1) ? W1 : (mat == 2) ? W2
                   : (mat == 3) ? W3 : W4;
    u16* o = wbuf + (size_t)mat * WSZ;
    int i = (blockIdx.x * 256 + threadIdx.x) * 4;
    float4 w = *(const float4*)(W + i);
    ushort4 h;
    h.x = f16b(w.x);
    h.y = f16b(w.y);
    h.z = f16b(w.z);
    h.w = f16b(w.w);
    *(ushort4*)(o + i) = h;
}

// ---------------------------------------------------------------------------
// Kernel 1: LayerNorm, coalesced 16-token tile (R9, kept).
// ---------------------------------------------------------------------------
__global__ __launch_bounds__(256) void ln_kernel(const float* __restrict__ x,
                                                 const float* __restrict__ gamma,
                                                 const float* __restrict__ beta,
                                                 u16* __restrict__ xh) {
    int b = blockIdx.y;
    int t0 = blockIdx.x * 16;
    int tid = threadIdx.x;
    int tx = tid & 15;          // t offset
    int cg = tid >> 4;          // c group 0..15
    const float* xb = x + (size_t)b * C_ * T_ + t0 + tx;

    float v[48];
    float s = 0.f, sq = 0.f;
    #pragma unroll
    for (int i = 0; i < 48; ++i) {
        float val = xb[(size_t)(i * 16 + cg) * T_];
        v[i] = val; s += val; sq += val * val;
    }
    __shared__ float rs_[16][16], rq_[16][16];   // [cg][tx]
    rs_[cg][tx] = s;
    rq_[cg][tx] = sq;
    __syncthreads();
    __shared__ float mu_[16], rstd_[16];
    if (tid < 16) {
        float S = 0.f, Q = 0.f;
        #pragma unroll
        for (int k = 0; k < 16; ++k) { S += rs_[k][tid]; Q += rq_[k][tid]; }
        float mu = S * (1.0f / 768.0f);
        float var = Q * (1.0f / 768.0f) - mu * mu;
        mu_[tid] = mu;
        rstd_[tid] = 1.0f / sqrtf(var + 1e-5f);
    }
    __syncthreads();
    float mu = mu_[tx], rstd = rstd_[tx];
    __shared__ u16 Lt[16][776];                  // +8 u16 pad
    #pragma unroll
    for (int i = 0; i < 48; ++i) {
        int c = i * 16 + cg;
        Lt[tx][c] = f16b((v[i] - mu) * rstd * gamma[c] + beta[c]);
    }
    __syncthreads();
    size_t obase = ((size_t)b * 1024 + t0) * C_;
    #pragma unroll
    for (int st = 0; st < 12; ++st) {
        int idx = st * 256 + tid;
        int t = idx / 192, c4 = idx % 192;
        *(ushort4*)(xh + obase + (size_t)t * C_ + c4 * 4) = *(ushort4*)&Lt[t][c4 * 4];
    }
}

// ---------------------------------------------------------------------------
// Kernel 2: fused QKVG GEMM, fp16 MFMA. EXACT R12 form -- measured floor of
// the 8-variant schedule ledger (90.4us). qkvg CLOSED.
// ---------------------------------------------------------------------------
__global__ __launch_bounds__(256, 3) void qkvg_mfma(
    const u16* __restrict__ xh, const u16* __restrict__ wmats,
    const float* __restrict__ bq, const float* __restrict__ bk,
    const float* __restrict__ bv, const float* __restrict__ bg,
    u16* __restrict__ qh, u16* __restrict__ kh,
    u16* __restrict__ vth, u16* __restrict__ g) {
    int bx = blockIdx.x;            // m tile 0..63
    int by = blockIdx.y;            // 0..23
    int mat = by / 6;
    int n0  = (by % 6) * 128;
    int m0  = bx * 128;
    const u16* Wh = wmats + (size_t)mat * WSZ;
    const float* bias = (mat == 0) ? bq : (mat == 1) ? bk : (mat == 2) ? bv : bg;

    __shared__ __attribute__((aligned(16))) u16 Ah[2 * 4096], Bh[2 * 4096];  // 32 KB

    int tid  = threadIdx.x;
    int lane = tid & 63, wid = tid >> 6;
    int wm = (wid & 1) * 64, wn = (wid >> 1) * 64;
    int fr = lane & 15, rq = (lane >> 4) * 4;

    f32x4 acc[4][4];
    #pragma unroll
    for (int i = 0; i < 4; ++i)
        #pragma unroll
        for (int j = 0; j < 4; ++j)
            acc[i][j] = (f32x4){0.f, 0.f, 0.f, 0.f};

    int ba = (wm >> 4), bb2 = (wn >> 4);

    // gld_lds staging: wave wid owns fragment blocks f0, f0+1
    int f0 = 2 * wid;
    const u16* gA0 = xh + (size_t)(m0 + f0 * 16 + fr) * 768 + (lane >> 4) * 8;
    const u16* gA1 = gA0 + (size_t)16 * 768;
    const u16* gB0 = Wh + (size_t)(n0 + f0 * 16 + fr) * 768 + (lane >> 4) * 8;
    const u16* gB1 = gB0 + (size_t)16 * 768;
    int la0 = f0 * 512 + lane * 8;   // u16 units; = uniform base + lane*16B
    int la1 = la0 + 512;

    #define STAGE(T, BUF) do { int kk0 = (T) * 32; int bo_ = (BUF) * 4096; \
        gld16(gA0 + kk0, Ah + bo_ + la0); \
        gld16(gA1 + kk0, Ah + bo_ + la1); \
        gld16(gB0 + kk0, Bh + bo_ + la0); \
        gld16(gB1 + kk0, Bh + bo_ + la1); \
    } while (0)

    STAGE(0, 0);
    __syncthreads();               // tile 0 staged (vmcnt drained by barrier)
    int cur = 0;
    for (int t = 0; t < 24; ++t) {
        int nxt = cur ^ 1;
        if (t + 1 < 24) STAGE(t + 1, nxt);   // issue; drains at bottom barrier
        int cb = cur * 4096;
        f16x8 fah[4], fbh[4];
        #pragma unroll
        for (int i = 0; i < 4; ++i) {
            fah[i] = *(const f16x8*)(Ah + cb + (ba + i) * 512 + lane * 8);
            fbh[i] = *(const f16x8*)(Bh + cb + (bb2 + i) * 512 + lane * 8);
        }
        if (mat == 2) {   // v: swapped operands -> transposed (token-minor) store
            #pragma unroll
            for (int mi = 0; mi < 4; ++mi)
                #pragma unroll
                for (int ni = 0; ni < 4; ++ni)
                    acc[mi][ni] = __builtin_amdgcn_mfma_f32_16x16x32_f16(fbh[ni], fah[mi], acc[mi][ni], 0, 0, 0);
        } else {
            #pragma unroll
            for (int mi = 0; mi < 4; ++mi)
                #pragma unroll
                for (int ni = 0; ni < 4; ++ni)
                    acc[mi][ni] = __builtin_amdgcn_mfma_f32_16x16x32_f16(fah[mi], fbh[ni], acc[mi][ni], 0, 0, 0);
        }
        __syncthreads();
        cur = nxt;
    }
    #undef STAGE
    // epilogue: C/D layout col=lane&15, row=(lane>>4)*4+reg
    if (mat == 2) {
        int bb = m0 >> 10;
        #pragma unroll
        for (int mi = 0; mi < 4; ++mi) {
            int tok = m0 + wm + mi * 16 + fr;
            int tl  = tok & 1023;
            #pragma unroll
            for (int ni = 0; ni < 4; ++ni) {
                #pragma unroll
                for (int rg = 0; rg < 4; ++rg) {
                    int ch = n0 + wn + ni * 16 + rq + rg;
                    float val = acc[mi][ni][rg] + bias[ch];
                    size_t addr = ((size_t)((bb * 12 + (ch >> 6)) * 64 + (ch & 63))) * 1024 + tl;
                    vth[addr] = f16b(val);
                }
            }
        }
    } else {
        u16* oh = (mat == 0) ? qh : (mat == 1) ? kh : g;
        float scale = (mat == 0) ? 0.125f : 1.0f;
        #pragma unroll
        for (int ni = 0; ni < 4; ++ni) {
            int col = n0 + wn + ni * 16 + fr;
            float bb = bias[col];
            #pragma unroll
            for (int mi = 0; mi < 4; ++mi) {
                int row = m0 + wm + mi * 16 + rq;
                #pragma unroll
                for (int rg = 0; rg < 4; ++rg) {
                    float val = (acc[mi][ni][rg] + bb) * scale;
                    oh[(size_t)(row + rg) * 768 + col] = f16b(val);
                }
            }
        }
    }
}

// ---------------------------------------------------------------------------
// Kernel 3: MFMA flash attention, fp16, swapped QK^T, QBLK=128, gld_lds K/V
// staging, setprio around MFMA clusters (R15).
// R16: SEPARATE Ps buffers per Q-strip (PsA/PsB). The shared Ps forced
// B's writes to wait on A's PV reads -> full A-chain (QK -> serial softmax
// -> PV) serialized before B's independent QK could issue. With split
// buffers the unrolled basic block lets the scheduler hoist B's QK MFMAs
// under A's softmax VALU (T15 mechanism, +7-11% m214v36). LDS 41->50 KB,
// still 3 blocks/CU (160/50). Zero numerics change.
// ---------------------------------------------------------------------------
__global__ __launch_bounds__(256, 3) void attn_mfma(
    const u16* __restrict__ qhg, const u16* __restrict__ khg,
    const u16* __restrict__ vthg, const u16* __restrict__ gbf,
    u16* __restrict__ yh) {
    int qt = blockIdx.x;   // 0..7 (128 q-rows)
    int h  = blockIdx.y;   // 0..11
    int b  = blockIdx.z;   // 0..7
    __shared__ __attribute__((aligned(16))) u16 Kh[2 * 4096], Vh[2 * 4096];
    __shared__ u16 PsA[64 * 72], PsB[64 * 72];
    int tid = threadIdx.x;
    int lane = tid & 63, w = tid >> 6;
    int fr = lane & 15, quad = lane >> 4, fq = quad * 8;

    size_t qbaseA = ((size_t)(b * 1024 + qt * 128)) * 768 + h * 64;
    size_t qbaseB = qbaseA + (size_t)64 * 768;
    size_t kbase = ((size_t)(b * 1024)) * 768 + h * 64;
    size_t vbase = ((size_t)((b * 12 + h) * 64)) * 1024;

    f16x8 aqA[2], aqB[2];
    #pragma unroll
    for (int kk = 0; kk < 2; ++kk) {
        size_t ro = (size_t)(w * 16 + fr) * 768 + kk * 32 + fq;
        aqA[kk] = *(const f16x8*)(qhg + qbaseA + ro);
        aqB[kk] = *(const f16x8*)(qhg + qbaseB + ro);
    }

    float m_A = -1e30f, l_A = 0.0f, m_B = -1e30f, l_B = 0.0f;
    f32x4 OA[4], OB[4];
    #pragma unroll
    for (int i = 0; i < 4; ++i) {
        OA[i] = (f32x4){0.f, 0.f, 0.f, 0.f};
        OB[i] = (f32x4){0.f, 0.f, 0.f, 0.f};
    }

    // gld_lds staging: wave w owns fragment blocks f0 = 2w, f0+1
    int f0 = 2 * w;
    int f1 = f0 + 1;
    const u16* kgA = khg + kbase + (size_t)((f0 & 3) * 16 + fr) * 768 + (f0 >> 2) * 32 + (lane >> 4) * 8;
    const u16* kgB = khg + kbase + (size_t)((f1 & 3) * 16 + fr) * 768 + (f1 >> 2) * 32 + (lane >> 4) * 8;
    const u16* vgA = vthg + vbase + (size_t)((f0 & 3) * 16 + fr) * 1024 + (f0 >> 2) * 32 + (lane >> 4) * 8;
    const u16* vgB = vthg + vbase + (size_t)((f1 & 3) * 16 + fr) * 1024 + (f1 >> 2) * 32 + (lane >> 4) * 8;
    int ldA = f0 * 512 + lane * 8;
    int ldB = ldA + 512;

    #define STAGE(ST, BUF) do { \
        size_t ko = (size_t)(ST) * 49152; \
        size_t vo = (size_t)(ST) * 64; \
        int bo_ = (BUF) * 4096; \
        gld16(kgA + ko, Kh + bo_ + ldA); \
        gld16(kgB + ko, Kh + bo_ + ldB); \
        gld16(vgA + vo, Vh + bo_ + ldA); \
        gld16(vgB + vo, Vh + bo_ + ldB); \
    } while (0)

    // one Q-strip against the staged K/V tile in buf[cur]; PS = private strip
    #define STRIP(AQ, MS, LS, OACC, PS) do { \
        f32x4 sacc[4]; \
        _Pragma("unroll") \
        for (int nt = 0; nt < 4; ++nt) sacc[nt] = (f32x4){0.f, 0.f, 0.f, 0.f}; \
        __builtin_amdgcn_s_setprio(1); \
        _Pragma("unroll") \
        for (int nt = 0; nt < 4; ++nt) \
            _Pragma("unroll") \
            for (int kk = 0; kk < 2; ++kk) { \
                f16x8 kb = *(const f16x8*)(Kh + cur * 4096 + (kk * 4 + nt) * 512 + lane * 8); \
                sacc[nt] = __builtin_amdgcn_mfma_f32_16x16x32_f16(kb, AQ[kk], sacc[nt], 0, 0, 0); \
            } \
        __builtin_amdgcn_s_setprio(0); \
        float mx = -1e30f; \
        _Pragma("unroll") \
        for (int nt = 0; nt < 4; ++nt) \
            _Pragma("unroll") \
            for (int rg = 0; rg < 4; ++rg) mx = fmaxf(mx, sacc[nt][rg]); \
        mx = fmaxf(mx, __shfl_xor(mx, 16)); \
        mx = fmaxf(mx, __shfl_xor(mx, 32)); \
        float mn = fmaxf(MS, mx); \
        float al = __expf(MS - mn); \
        MS = mn; \
        float rs = 0.0f; \
        _Pragma("unroll") \
        for (int nt = 0; nt < 4; ++nt) \
            _Pragma("unroll") \
            for (int rg = 0; rg < 4; ++rg) { \
                float p = __expf(sacc[nt][rg] - mn); \
                sacc[nt][rg] = p; \
                rs += p; \
            } \
        rs += __shfl_xor(rs, 16); \
        rs += __shfl_xor(rs, 32); \
        LS = LS * al + rs; \
        int prow = (w * 16 + fr) * 72; \
        _Pragma("unroll") \
        for (int nt = 0; nt < 4; ++nt) { \
            ushort4 hp; \
            hp.x = f16b(sacc[nt][0]); \
            hp.y = f16b(sacc[nt][1]); \
            hp.z = f16b(sacc[nt][2]); \
            hp.w = f16b(sacc[nt][3]); \
            *(ushort4*)&PS[prow + nt * 16 + quad * 4] = hp; \
        } \
        float alr[4]; \
        _Pragma("unroll") \
        for (int rg = 0; rg < 4; ++rg) alr[rg] = __shfl(al, quad * 4 + rg, 16); \
        _Pragma("unroll") \
        for (int dn = 0; dn < 4; ++dn) \
            _Pragma("unroll") \
            for (int rg = 0; rg < 4; ++rg) OACC[dn][rg] *= alr[rg]; \
        __builtin_amdgcn_s_setprio(1); \
        _Pragma("unroll") \
        for (int kk = 0; kk < 2; ++kk) { \
            f16x8 pa = *(const f16x8*)&PS[(w * 16 + fr) * 72 + fq + kk * 32]; \
            _Pragma("unroll") \
            for (int dn = 0; dn < 4; ++dn) { \
                f16x8 vb = *(const f16x8*)(Vh + cur * 4096 + (kk * 4 + dn) * 512 + lane * 8); \
                OACC[dn] = __builtin_amdgcn_mfma_f32_16x16x32_f16(pa, vb, OACC[dn], 0, 0, 0); \
            } \
        } \
        __builtin_amdgcn_s_setprio(0); \
    } while (0)

    STAGE(0, 0);
    __syncthreads();               // st0 staged (vmcnt drained by barrier)
    int cur = 0;
    for (int st = 0; st < 16; ++st) {
        int nxt = cur ^ 1;
        if (st + 1 < 16) STAGE(st + 1, nxt);   // issue; drains at bottom barrier
        STRIP(aqA, m_A, l_A, OA, PsA);
        STRIP(aqB, m_B, l_B, OB, PsB);
        __syncthreads();
        cur = nxt;
    }
    #undef STAGE
    #undef STRIP
    // epilogue: normalize, sigmoid gate, fp16 y store (both strips)
    float invA[4], invB[4];
    #pragma unroll
    for (int rg = 0; rg < 4; ++rg) {
        invA[rg] = 1.0f / __shfl(l_A, quad * 4 + rg, 16);
        invB[rg] = 1.0f / __shfl(l_B, quad * 4 + rg, 16);
    }
    int tokA0 = b * 1024 + qt * 128 + w * 16;
    #pragma unroll
    for (int dn = 0; dn < 4; ++dn) {
        int ch = h * 64 + dn * 16 + fr;
        #pragma unroll
        for (int rg = 0; rg < 4; ++rg) {
            int tok = tokA0 + quad * 4 + rg;
            float gv = f16f(gbf[(size_t)tok * 768 + ch]);
            float sg = 1.0f / (1.0f + __expf(-gv));
            yh[(size_t)tok * 768 + ch] = f16b(OA[dn][rg] * invA[rg] * sg);
            int tok2 = tok + 64;
            float gv2 = f16f(gbf[(size_t)tok2 * 768 + ch]);
            float sg2 = 1.0f / (1.0f + __expf(-gv2));
            yh[(size_t)tok2 * 768 + ch] = f16b(OB[dn][rg] * invB[rg] * sg2);
        }
    }
}

// ---------------------------------------------------------------------------
// Kernel 4: out = y @ Wo^T + bo -> (B, C, T). Exact R12 gld_lds DB form.
// ---------------------------------------------------------------------------
__global__ __launch_bounds__(256, 3) void out_mfma(
    const u16* __restrict__ yh, const u16* __restrict__ woh,
    const float* __restrict__ bo, float* __restrict__ out) {
    int bx = blockIdx.x;   // c tile 0..5
    int by = blockIdx.y;   // t tile 0..63
    int m0 = bx * 128;     // c
    int n0 = by * 128;     // t

    __shared__ __attribute__((aligned(16))) u16 Ah[2 * 4096], Bh[2 * 4096];  // 32 KB

    int tid  = threadIdx.x;
    int lane = tid & 63, wid = tid >> 6;
    int wm = (wid & 1) * 64, wn = (wid >> 1) * 64;
    int fr = lane & 15, rq = (lane >> 4) * 4;

    f32x4 acc[4][4];
    #pragma unroll
    for (int i = 0; i < 4; ++i)
        #pragma unroll
        for (int j = 0; j < 4; ++j)
            acc[i][j] = (f32x4){0.f, 0.f, 0.f, 0.f};

    int ba = (wm >> 4), bb2 = (wn >> 4);

    int f0 = 2 * wid;
    const u16* gA0 = woh + (size_t)(m0 + f0 * 16 + fr) * 768 + (lane >> 4) * 8;
    const u16* gA1 = gA0 + (size_t)16 * 768;
    const u16* gB0 = yh + (size_t)(n0 + f0 * 16 + fr) * 768 + (lane >> 4) * 8;
    const u16* gB1 = gB0 + (size_t)16 * 768;
    int la0 = f0 * 512 + lane * 8;
    int la1 = la0 + 512;

    #define STAGE(T, BUF) do { int kk0 = (T) * 32; int bo_ = (BUF) * 4096; \
        gld16(gA0 + kk0, Ah + bo_ + la0); \
        gld16(gA1 + kk0, Ah + bo_ + la1); \
        gld16(gB0 + kk0, Bh + bo_ + la0); \
        gld16(gB1 + kk0, Bh + bo_ + la1); \
    } while (0)

    STAGE(0, 0);
    __syncthreads();
    int cur = 0;
    for (int t = 0; t < 24; ++t) {
        int nxt = cur ^ 1;
        if (t + 1 < 24) STAGE(t + 1, nxt);
        int cb = cur * 4096;
        f16x8 fah[4], fbh[4];
        #pragma unroll
        for (int i = 0; i < 4; ++i) {
            fah[i] = *(const f16x8*)(Ah + cb + (ba + i) * 512 + lane * 8);
            fbh[i] = *(const f16x8*)(Bh + cb + (bb2 + i) * 512 + lane * 8);
        }
        #pragma unroll
        for (int mi = 0; mi < 4; ++mi)
            #pragma unroll
            for (int ni = 0; ni < 4; ++ni)
                acc[mi][ni] = __builtin_amdgcn_mfma_f32_16x16x32_f16(fah[mi], fbh[ni], acc[mi][ni], 0, 0, 0);
        __syncthreads();
        cur = nxt;
    }
    #undef STAGE
    int bb = n0 >> 10;
    #pragma unroll
    for (int ni = 0; ni < 4; ++ni) {
        int colg = n0 + wn + ni * 16 + fr;
        int tl = colg & 1023;
        #pragma unroll
        for (int mi = 0; mi < 4; ++mi) {
            int row = m0 + wm + mi * 16 + rq;
            #pragma unroll
            for (int rg = 0; rg < 4; ++rg) {
                float val = acc[mi][ni][rg] + bo[row + rg];
                out[((size_t)bb * 768 + row + rg) * 1024 + tl] = val;
            }
        }
    }
}

extern "C" void kernel_launch(void* const* d_in, const int* in_sizes, int n_in,
                              void* d_out, int out_size, void* d_ws, size_t ws_size,
                              hipStream_t stream) {
    const float* x     = (const float*)d_in[0];
    const float* Wq    = (const float*)d_in[1];
    const float* bq    = (const float*)d_in[2];
    const float* Wk    = (const float*)d_in[3];
    const float* bk    = (const float*)d_in[4];
    const float* Wv    = (const float*)d_in[5];
    const float* bv    = (const float*)d_in[6];
    const float* Wo    = (const float*)d_in[7];
    const float* bo    = (const float*)d_in[8];
    const float* Wg    = (const float*)d_in[9];
    const float* bg    = (const float*)d_in[10];
    const float* gamma = (const float*)d_in[11];
    const float* beta  = (const float*)d_in[12];
    float* out = (float*)d_out;

    // workspace (ushort, all fp16): xn|q|k|vt|g | wbuf[Wq,Wk,Wv,Wg,Wo]
    const size_t S = (size_t)BT_ * C_;
    u16* xn   = (u16*)d_ws;
    u16* qh   = xn + S;
    u16* kh   = qh + S;
    u16* vth  = kh + S;
    u16* g_bf = vth + S;
    u16* wbuf = g_bf + S;
    u16* y_h  = xn;          // alias: xn dead after qkvg

    wconv_all<<<dim3(WSZ / 1024, 5), 256, 0, stream>>>(Wq, Wk, Wv, Wg, Wo, wbuf);
    ln_kernel<<<dim3(64, 8), 256, 0, stream>>>(x, gamma, beta, xn);
    qkvg_mfma<<<dim3(64, 24), 256, 0, stream>>>(xn, wbuf, bq, bk, bv, bg,
                                                qh, kh, vth, g_bf);
    attn_mfma<<<dim3(8, 12, 8), 256, 0, stream>>>(qh, kh, vth, g_bf, y_h);
    out_mfma<<<dim3(6, 64), 256, 0, stream>>>(y_h, wbuf + (size_t)4 * WSZ, bo, out);
}

// Round 17
// 272.623 us; speedup vs baseline: 1.2825x; 1.0010x over previous
//
#include <hip/hip_runtime.h>
#include <math.h>

#define B_   8
#define C_   768
#define T_   1024
#define BT_  (B_*T_)       // 8192
#define WSZ  (C_*C_)       // 589824 per weight matrix

using f16x8 = __attribute__((ext_vector_type(8))) _Float16;
using f32x4 = __attribute__((ext_vector_type(4))) float;
typedef unsigned short u16;

// ---- fp16 helpers ----
__device__ inline u16 f16b(float x) {
    _Float16 h = (_Float16)x;
    return __builtin_bit_cast(u16, h);
}
__device__ inline float f16f(u16 b) {
    return (float)__builtin_bit_cast(_Float16, b);
}

// Direct global->LDS DMA, 16B/lane. HW: dest = readfirstlane(ptr) + lane*16.
// Callers pass lds = base + lane*8 (u16), base wave-uniform. (R3/R11/R12-verified.)
typedef const __attribute__((address_space(1))) unsigned int gas_uint;
typedef __attribute__((address_space(3))) unsigned int las_uint;
__device__ inline void gld16(const u16* __restrict__ g, u16* l) {
    __builtin_amdgcn_global_load_lds((gas_uint*)g, (las_uint*)l, 16, 0, 0);
}

// ---------------------------------------------------------------------------
// Kernel 0: all 5 weight mats fp32 -> fp16 in one launch.
// ---------------------------------------------------------------------------
__global__ __launch_bounds__(256) void wconv_all(
    const float* __restrict__ W0, const float* __restrict__ W1,
    const float* __restrict__ W2, const float* __restrict__ W3,
    const float* __restrict__ W4, u16* __restrict__ wbuf) {
    int mat = blockIdx.y;
    const float* W = (mat == 0) ? W0 : (mat == 1) ? W1 : (mat == 2) ? W2
                   : (mat == 3) ? W3 : W4;
    u16* o = wbuf + (size_t)mat * WSZ;
    int i = (blockIdx.x * 256 + threadIdx.x) * 4;
    float4 w = *(const float4*)(W + i);
    ushort4 h;
    h.x = f16b(w.x);
    h.y = f16b(w.y);
    h.z = f16b(w.z);
    h.w = f16b(w.w);
    *(ushort4*)(o + i) = h;
}

// ---------------------------------------------------------------------------
// Kernel 1: LayerNorm, coalesced 16-token tile (R9, kept).
// ---------------------------------------------------------------------------
__global__ __launch_bounds__(256) void ln_kernel(const float* __restrict__ x,
                                                 const float* __restrict__ gamma,
                                                 const float* __restrict__ beta,
                                                 u16* __restrict__ xh) {
    int b = blockIdx.y;
    int t0 = blockIdx.x * 16;
    int tid = threadIdx.x;
    int tx = tid & 15;          // t offset
    int cg = tid >> 4;          // c group 0..15
    const float* xb = x + (size_t)b * C_ * T_ + t0 + tx;

    float v[48];
    float s = 0.f, sq = 0.f;
    #pragma unroll
    for (int i = 0; i < 48; ++i) {
        float val = xb[(size_t)(i * 16 + cg) * T_];
        v[i] = val; s += val; sq += val * val;
    }
    __shared__ float rs_[16][16], rq_[16][16];   // [cg][tx]
    rs_[cg][tx] = s;
    rq_[cg][tx] = sq;
    __syncthreads();
    __shared__ float mu_[16], rstd_[16];
    if (tid < 16) {
        float S = 0.f, Q = 0.f;
        #pragma unroll
        for (int k = 0; k < 16; ++k) { S += rs_[k][tid]; Q += rq_[k][tid]; }
        float mu = S * (1.0f / 768.0f);
        float var = Q * (1.0f / 768.0f) - mu * mu;
        mu_[tid] = mu;
        rstd_[tid] = 1.0f / sqrtf(var + 1e-5f);
    }
    __syncthreads();
    float mu = mu_[tx], rstd = rstd_[tx];
    __shared__ u16 Lt[16][776];                  // +8 u16 pad
    #pragma unroll
    for (int i = 0; i < 48; ++i) {
        int c = i * 16 + cg;
        Lt[tx][c] = f16b((v[i] - mu) * rstd * gamma[c] + beta[c]);
    }
    __syncthreads();
    size_t obase = ((size_t)b * 1024 + t0) * C_;
    #pragma unroll
    for (int st = 0; st < 12; ++st) {
        int idx = st * 256 + tid;
        int t = idx / 192, c4 = idx % 192;
        *(ushort4*)(xh + obase + (size_t)t * C_ + c4 * 4) = *(ushort4*)&Lt[t][c4 * 4];
    }
}

// ---------------------------------------------------------------------------
// Kernel 2: fused QKVG GEMM, fp16 MFMA. EXACT R12 form -- measured floor of
// the 8-variant schedule ledger (90.4us). qkvg CLOSED.
// ---------------------------------------------------------------------------
__global__ __launch_bounds__(256, 3) void qkvg_mfma(
    const u16* __restrict__ xh, const u16* __restrict__ wmats,
    const float* __restrict__ bq, const float* __restrict__ bk,
    const float* __restrict__ bv, const float* __restrict__ bg,
    u16* __restrict__ qh, u16* __restrict__ kh,
    u16* __restrict__ vth, u16* __restrict__ g) {
    int bx = blockIdx.x;            // m tile 0..63
    int by = blockIdx.y;            // 0..23
    int mat = by / 6;
    int n0  = (by % 6) * 128;
    int m0  = bx * 128;
    const u16* Wh = wmats + (size_t)mat * WSZ;
    const float* bias = (mat == 0) ? bq : (mat == 1) ? bk : (mat == 2) ? bv : bg;

    __shared__ __attribute__((aligned(16))) u16 Ah[2 * 4096], Bh[2 * 4096];  // 32 KB

    int tid  = threadIdx.x;
    int lane = tid & 63, wid = tid >> 6;
    int wm = (wid & 1) * 64, wn = (wid >> 1) * 64;
    int fr = lane & 15, rq = (lane >> 4) * 4;

    f32x4 acc[4][4];
    #pragma unroll
    for (int i = 0; i < 4; ++i)
        #pragma unroll
        for (int j = 0; j < 4; ++j)
            acc[i][j] = (f32x4){0.f, 0.f, 0.f, 0.f};

    int ba = (wm >> 4), bb2 = (wn >> 4);

    // gld_lds staging: wave wid owns fragment blocks f0, f0+1
    int f0 = 2 * wid;
    const u16* gA0 = xh + (size_t)(m0 + f0 * 16 + fr) * 768 + (lane >> 4) * 8;
    const u16* gA1 = gA0 + (size_t)16 * 768;
    const u16* gB0 = Wh + (size_t)(n0 + f0 * 16 + fr) * 768 + (lane >> 4) * 8;
    const u16* gB1 = gB0 + (size_t)16 * 768;
    int la0 = f0 * 512 + lane * 8;   // u16 units; = uniform base + lane*16B
    int la1 = la0 + 512;

    #define STAGE(T, BUF) do { int kk0 = (T) * 32; int bo_ = (BUF) * 4096; \
        gld16(gA0 + kk0, Ah + bo_ + la0); \
        gld16(gA1 + kk0, Ah + bo_ + la1); \
        gld16(gB0 + kk0, Bh + bo_ + la0); \
        gld16(gB1 + kk0, Bh + bo_ + la1); \
    } while (0)

    STAGE(0, 0);
    __syncthreads();               // tile 0 staged (vmcnt drained by barrier)
    int cur = 0;
    for (int t = 0; t < 24; ++t) {
        int nxt = cur ^ 1;
        if (t + 1 < 24) STAGE(t + 1, nxt);   // issue; drains at bottom barrier
        int cb = cur * 4096;
        f16x8 fah[4], fbh[4];
        #pragma unroll
        for (int i = 0; i < 4; ++i) {
            fah[i] = *(const f16x8*)(Ah + cb + (ba + i) * 512 + lane * 8);
            fbh[i] = *(const f16x8*)(Bh + cb + (bb2 + i) * 512 + lane * 8);
        }
        if (mat == 2) {   // v: swapped operands -> transposed (token-minor) store
            #pragma unroll
            for (int mi = 0; mi < 4; ++mi)
                #pragma unroll
                for (int ni = 0; ni < 4; ++ni)
                    acc[mi][ni] = __builtin_amdgcn_mfma_f32_16x16x32_f16(fbh[ni], fah[mi], acc[mi][ni], 0, 0, 0);
        } else {
            #pragma unroll
            for (int mi = 0; mi < 4; ++mi)
                #pragma unroll
                for (int ni = 0; ni < 4; ++ni)
                    acc[mi][ni] = __builtin_amdgcn_mfma_f32_16x16x32_f16(fah[mi], fbh[ni], acc[mi][ni], 0, 0, 0);
        }
        __syncthreads();
        cur = nxt;
    }
    #undef STAGE
    // epilogue: C/D layout col=lane&15, row=(lane>>4)*4+reg
    if (mat == 2) {
        int bb = m0 >> 10;
        #pragma unroll
        for (int mi = 0; mi < 4; ++mi) {
            int tok = m0 + wm + mi * 16 + fr;
            int tl  = tok & 1023;
            #pragma unroll
            for (int ni = 0; ni < 4; ++ni) {
                #pragma unroll
                for (int rg = 0; rg < 4; ++rg) {
                    int ch = n0 + wn + ni * 16 + rq + rg;
                    float val = acc[mi][ni][rg] + bias[ch];
                    size_t addr = ((size_t)((bb * 12 + (ch >> 6)) * 64 + (ch & 63))) * 1024 + tl;
                    vth[addr] = f16b(val);
                }
            }
        }
    } else {
        u16* oh = (mat == 0) ? qh : (mat == 1) ? kh : g;
        float scale = (mat == 0) ? 0.125f : 1.0f;
        #pragma unroll
        for (int ni = 0; ni < 4; ++ni) {
            int col = n0 + wn + ni * 16 + fr;
            float bb = bias[col];
            #pragma unroll
            for (int mi = 0; mi < 4; ++mi) {
                int row = m0 + wm + mi * 16 + rq;
                #pragma unroll
                for (int rg = 0; rg < 4; ++rg) {
                    float val = (acc[mi][ni][rg] + bb) * scale;
                    oh[(size_t)(row + rg) * 768 + col] = f16b(val);
                }
            }
        }
    }
}

// ---------------------------------------------------------------------------
// Kernel 3: MFMA flash attention, fp16, swapped QK^T, QBLK=128, gld_lds K/V
// staging, setprio, split PsA/PsB (R16).
// R17: T13 defer-max (m214v23/v28, m239: +5%, refcheck'd THR=8). When the
// tile max is within 8 of the running max (wave-uniform __all), keep m ->
// al=1 -> skip the entire rescale pass (LS*al, 4 alr shuffles, 16 Oacc
// mults). P = exp(s - m_old) <= e^8 = 2981, inside fp16 range; relative
// rounding unchanged (scale cancels at normalization). First tile always
// rescales (m = -1e30).
// ---------------------------------------------------------------------------
__global__ __launch_bounds__(256, 3) void attn_mfma(
    const u16* __restrict__ qhg, const u16* __restrict__ khg,
    const u16* __restrict__ vthg, const u16* __restrict__ gbf,
    u16* __restrict__ yh) {
    int qt = blockIdx.x;   // 0..7 (128 q-rows)
    int h  = blockIdx.y;   // 0..11
    int b  = blockIdx.z;   // 0..7
    __shared__ __attribute__((aligned(16))) u16 Kh[2 * 4096], Vh[2 * 4096];
    __shared__ u16 PsA[64 * 72], PsB[64 * 72];
    int tid = threadIdx.x;
    int lane = tid & 63, w = tid >> 6;
    int fr = lane & 15, quad = lane >> 4, fq = quad * 8;

    size_t qbaseA = ((size_t)(b * 1024 + qt * 128)) * 768 + h * 64;
    size_t qbaseB = qbaseA + (size_t)64 * 768;
    size_t kbase = ((size_t)(b * 1024)) * 768 + h * 64;
    size_t vbase = ((size_t)((b * 12 + h) * 64)) * 1024;

    f16x8 aqA[2], aqB[2];
    #pragma unroll
    for (int kk = 0; kk < 2; ++kk) {
        size_t ro = (size_t)(w * 16 + fr) * 768 + kk * 32 + fq;
        aqA[kk] = *(const f16x8*)(qhg + qbaseA + ro);
        aqB[kk] = *(const f16x8*)(qhg + qbaseB + ro);
    }

    float m_A = -1e30f, l_A = 0.0f, m_B = -1e30f, l_B = 0.0f;
    f32x4 OA[4], OB[4];
    #pragma unroll
    for (int i = 0; i < 4; ++i) {
        OA[i] = (f32x4){0.f, 0.f, 0.f, 0.f};
        OB[i] = (f32x4){0.f, 0.f, 0.f, 0.f};
    }

    // gld_lds staging: wave w owns fragment blocks f0 = 2w, f0+1
    int f0 = 2 * w;
    int f1 = f0 + 1;
    const u16* kgA = khg + kbase + (size_t)((f0 & 3) * 16 + fr) * 768 + (f0 >> 2) * 32 + (lane >> 4) * 8;
    const u16* kgB = khg + kbase + (size_t)((f1 & 3) * 16 + fr) * 768 + (f1 >> 2) * 32 + (lane >> 4) * 8;
    const u16* vgA = vthg + vbase + (size_t)((f0 & 3) * 16 + fr) * 1024 + (f0 >> 2) * 32 + (lane >> 4) * 8;
    const u16* vgB = vthg + vbase + (size_t)((f1 & 3) * 16 + fr) * 1024 + (f1 >> 2) * 32 + (lane >> 4) * 8;
    int ldA = f0 * 512 + lane * 8;
    int ldB = ldA + 512;

    #define STAGE(ST, BUF) do { \
        size_t ko = (size_t)(ST) * 49152; \
        size_t vo = (size_t)(ST) * 64; \
        int bo_ = (BUF) * 4096; \
        gld16(kgA + ko, Kh + bo_ + ldA); \
        gld16(kgB + ko, Kh + bo_ + ldB); \
        gld16(vgA + vo, Vh + bo_ + ldA); \
        gld16(vgB + vo, Vh + bo_ + ldB); \
    } while (0)

    // one Q-strip against the staged K/V tile in buf[cur]; PS = private strip
    #define STRIP(AQ, MS, LS, OACC, PS) do { \
        f32x4 sacc[4]; \
        _Pragma("unroll") \
        for (int nt = 0; nt < 4; ++nt) sacc[nt] = (f32x4){0.f, 0.f, 0.f, 0.f}; \
        __builtin_amdgcn_s_setprio(1); \
        _Pragma("unroll") \
        for (int nt = 0; nt < 4; ++nt) \
            _Pragma("unroll") \
            for (int kk = 0; kk < 2; ++kk) { \
                f16x8 kb = *(const f16x8*)(Kh + cur * 4096 + (kk * 4 + nt) * 512 + lane * 8); \
                sacc[nt] = __builtin_amdgcn_mfma_f32_16x16x32_f16(kb, AQ[kk], sacc[nt], 0, 0, 0); \
            } \
        __builtin_amdgcn_s_setprio(0); \
        float mx = -1e30f; \
        _Pragma("unroll") \
        for (int nt = 0; nt < 4; ++nt) \
            _Pragma("unroll") \
            for (int rg = 0; rg < 4; ++rg) mx = fmaxf(mx, sacc[nt][rg]); \
        mx = fmaxf(mx, __shfl_xor(mx, 16)); \
        mx = fmaxf(mx, __shfl_xor(mx, 32)); \
        if (!__all(mx <= MS + 8.0f)) {   /* T13: rescale only on real growth */ \
            float mn = fmaxf(MS, mx); \
            float al = __expf(MS - mn); \
            MS = mn; \
            LS *= al; \
            float alr[4]; \
            _Pragma("unroll") \
            for (int rg = 0; rg < 4; ++rg) alr[rg] = __shfl(al, quad * 4 + rg, 16); \
            _Pragma("unroll") \
            for (int dn = 0; dn < 4; ++dn) \
                _Pragma("unroll") \
                for (int rg = 0; rg < 4; ++rg) OACC[dn][rg] *= alr[rg]; \
        } \
        float rs = 0.0f; \
        _Pragma("unroll") \
        for (int nt = 0; nt < 4; ++nt) \
            _Pragma("unroll") \
            for (int rg = 0; rg < 4; ++rg) { \
                float p = __expf(sacc[nt][rg] - MS); \
                sacc[nt][rg] = p; \
                rs += p; \
            } \
        rs += __shfl_xor(rs, 16); \
        rs += __shfl_xor(rs, 32); \
        LS += rs; \
        int prow = (w * 16 + fr) * 72; \
        _Pragma("unroll") \
        for (int nt = 0; nt < 4; ++nt) { \
            ushort4 hp; \
            hp.x = f16b(sacc[nt][0]); \
            hp.y = f16b(sacc[nt][1]); \
            hp.z = f16b(sacc[nt][2]); \
            hp.w = f16b(sacc[nt][3]); \
            *(ushort4*)&PS[prow + nt * 16 + quad * 4] = hp; \
        } \
        __builtin_amdgcn_s_setprio(1); \
        _Pragma("unroll") \
        for (int kk = 0; kk < 2; ++kk) { \
            f16x8 pa = *(const f16x8*)&PS[(w * 16 + fr) * 72 + fq + kk * 32]; \
            _Pragma("unroll") \
            for (int dn = 0; dn < 4; ++dn) { \
                f16x8 vb = *(const f16x8*)(Vh + cur * 4096 + (kk * 4 + dn) * 512 + lane * 8); \
                OACC[dn] = __builtin_amdgcn_mfma_f32_16x16x32_f16(pa, vb, OACC[dn], 0, 0, 0); \
            } \
        } \
        __builtin_amdgcn_s_setprio(0); \
    } while (0)

    STAGE(0, 0);
    __syncthreads();               // st0 staged (vmcnt drained by barrier)
    int cur = 0;
    for (int st = 0; st < 16; ++st) {
        int nxt = cur ^ 1;
        if (st + 1 < 16) STAGE(st + 1, nxt);   // issue; drains at bottom barrier
        STRIP(aqA, m_A, l_A, OA, PsA);
        STRIP(aqB, m_B, l_B, OB, PsB);
        __syncthreads();
        cur = nxt;
    }
    #undef STAGE
    #undef STRIP
    // epilogue: normalize, sigmoid gate, fp16 y store (both strips)
    float invA[4], invB[4];
    #pragma unroll
    for (int rg = 0; rg < 4; ++rg) {
        invA[rg] = 1.0f / __shfl(l_A, quad * 4 + rg, 16);
        invB[rg] = 1.0f / __shfl(l_B, quad * 4 + rg, 16);
    }
    int tokA0 = b * 1024 + qt * 128 + w * 16;
    #pragma unroll
    for (int dn = 0; dn < 4; ++dn) {
        int ch = h * 64 + dn * 16 + fr;
        #pragma unroll
        for (int rg = 0; rg < 4; ++rg) {
            int tok = tokA0 + quad * 4 + rg;
            float gv = f16f(gbf[(size_t)tok * 768 + ch]);
            float sg = 1.0f / (1.0f + __expf(-gv));
            yh[(size_t)tok * 768 + ch] = f16b(OA[dn][rg] * invA[rg] * sg);
            int tok2 = tok + 64;
            float gv2 = f16f(gbf[(size_t)tok2 * 768 + ch]);
            float sg2 = 1.0f / (1.0f + __expf(-gv2));
            yh[(size_t)tok2 * 768 + ch] = f16b(OB[dn][rg] * invB[rg] * sg2);
        }
    }
}

// ---------------------------------------------------------------------------
// Kernel 4: out = y @ Wo^T + bo -> (B, C, T). Exact R12 gld_lds DB form.
// ---------------------------------------------------------------------------
__global__ __launch_bounds__(256, 3) void out_mfma(
    const u16* __restrict__ yh, const u16* __restrict__ woh,
    const float* __restrict__ bo, float* __restrict__ out) {
    int bx = blockIdx.x;   // c tile 0..5
    int by = blockIdx.y;   // t tile 0..63
    int m0 = bx * 128;     // c
    int n0 = by * 128;     // t

    __shared__ __attribute__((aligned(16))) u16 Ah[2 * 4096], Bh[2 * 4096];  // 32 KB

    int tid  = threadIdx.x;
    int lane = tid & 63, wid = tid >> 6;
    int wm = (wid & 1) * 64, wn = (wid >> 1) * 64;
    int fr = lane & 15, rq = (lane >> 4) * 4;

    f32x4 acc[4][4];
    #pragma unroll
    for (int i = 0; i < 4; ++i)
        #pragma unroll
        for (int j = 0; j < 4; ++j)
            acc[i][j] = (f32x4){0.f, 0.f, 0.f, 0.f};

    int ba = (wm >> 4), bb2 = (wn >> 4);

    int f0 = 2 * wid;
    const u16* gA0 = woh + (size_t)(m0 + f0 * 16 + fr) * 768 + (lane >> 4) * 8;
    const u16* gA1 = gA0 + (size_t)16 * 768;
    const u16* gB0 = yh + (size_t)(n0 + f0 * 16 + fr) * 768 + (lane >> 4) * 8;
    const u16* gB1 = gB0 + (size_t)16 * 768;
    int la0 = f0 * 512 + lane * 8;
    int la1 = la0 + 512;

    #define STAGE(T, BUF) do { int kk0 = (T) * 32; int bo_ = (BUF) * 4096; \
        gld16(gA0 + kk0, Ah + bo_ + la0); \
        gld16(gA1 + kk0, Ah + bo_ + la1); \
        gld16(gB0 + kk0, Bh + bo_ + la0); \
        gld16(gB1 + kk0, Bh + bo_ + la1); \
    } while (0)

    STAGE(0, 0);
    __syncthreads();
    int cur = 0;
    for (int t = 0; t < 24; ++t) {
        int nxt = cur ^ 1;
        if (t + 1 < 24) STAGE(t + 1, nxt);
        int cb = cur * 4096;
        f16x8 fah[4], fbh[4];
        #pragma unroll
        for (int i = 0; i < 4; ++i) {
            fah[i] = *(const f16x8*)(Ah + cb + (ba + i) * 512 + lane * 8);
            fbh[i] = *(const f16x8*)(Bh + cb + (bb2 + i) * 512 + lane * 8);
        }
        #pragma unroll
        for (int mi = 0; mi < 4; ++mi)
            #pragma unroll
            for (int ni = 0; ni < 4; ++ni)
                acc[mi][ni] = __builtin_amdgcn_mfma_f32_16x16x32_f16(fah[mi], fbh[ni], acc[mi][ni], 0, 0, 0);
        __syncthreads();
        cur = nxt;
    }
    #undef STAGE
    int bb = n0 >> 10;
    #pragma unroll
    for (int ni = 0; ni < 4; ++ni) {
        int colg = n0 + wn + ni * 16 + fr;
        int tl = colg & 1023;
        #pragma unroll
        for (int mi = 0; mi < 4; ++mi) {
            int row = m0 + wm + mi * 16 + rq;
            #pragma unroll
            for (int rg = 0; rg < 4; ++rg) {
                float val = acc[mi][ni][rg] + bo[row + rg];
                out[((size_t)bb * 768 + row + rg) * 1024 + tl] = val;
            }
        }
    }
}

extern "C" void kernel_launch(void* const* d_in, const int* in_sizes, int n_in,
                              void* d_out, int out_size, void* d_ws, size_t ws_size,
                              hipStream_t stream) {
    const float* x     = (const float*)d_in[0];
    const float* Wq    = (const float*)d_in[1];
    const float* bq    = (const float*)d_in[2];
    const float* Wk    = (const float*)d_in[3];
    const float* bk    = (const float*)d_in[4];
    const float* Wv    = (const float*)d_in[5];
    const float* bv    = (const float*)d_in[6];
    const float* Wo    = (const float*)d_in[7];
    const float* bo    = (const float*)d_in[8];
    const float* Wg    = (const float*)d_in[9];
    const float* bg    = (const float*)d_in[10];
    const float* gamma = (const float*)d_in[11];
    const float* beta  = (const float*)d_in[12];
    float* out = (float*)d_out;

    // workspace (ushort, all fp16): xn|q|k|vt|g | wbuf[Wq,Wk,Wv,Wg,Wo]
    const size_t S = (size_t)BT_ * C_;
    u16* xn   = (u16*)d_ws;
    u16* qh   = xn + S;
    u16* kh   = qh + S;
    u16* vth  = kh + S;
    u16* g_bf = vth + S;
    u16* wbuf = g_bf + S;
    u16* y_h  = xn;          // alias: xn dead after qkvg

    wconv_all<<<dim3(WSZ / 1024, 5), 256, 0, stream>>>(Wq, Wk, Wv, Wg, Wo, wbuf);
    ln_kernel<<<dim3(64, 8), 256, 0, stream>>>(x, gamma, beta, xn);
    qkvg_mfma<<<dim3(64, 24), 256, 0, stream>>>(xn, wbuf, bq, bk, bv, bg,
                                                qh, kh, vth, g_bf);
    attn_mfma<<<dim3(8, 12, 8), 256, 0, stream>>>(qh, kh, vth, g_bf, y_h);
    out_mfma<<<dim3(6, 64), 256, 0, stream>>>(y_h, wbuf + (size_t)4 * WSZ, bo, out);
}